// Round 12
// baseline (1166.061 us; speedup 1.0000x reference)
//
#include <hip/hip_runtime.h>
#include <hip/hip_fp16.h>

#define BB 2048
#define SS 512
#define FF 32
#define HH 128
#define TO 24
#define LOG2E 1.4426950408889634f

typedef unsigned int uint;
using half2v = __attribute__((ext_vector_type(2))) _Float16;
using half4 = __attribute__((ext_vector_type(4))) _Float16;
using half8 = __attribute__((ext_vector_type(8))) _Float16;
using f32x4 = __attribute__((ext_vector_type(4))) float;

// ---- workspace layout (bytes) ----
#define OFF_ENCOUT 0ull                                      // half[B][S][H]
#define OFF_HFIN  (OFF_ENCOUT + (size_t)BB*SS*HH*2)          // float[B][H]
#define OFF_ATTNF (OFF_HFIN + (size_t)BB*HH*4)               // half[65536]  fused logits B-frags (K=128)
#define OFF_ATTNB (OFF_ATTNF + (size_t)65536*2)              // float[512]   fused logit bias
#define OFF_DECF  (OFF_ATTNB + (size_t)512*4)                // half[98304]  GRU B-frags
#define OFF_OUT1F (OFF_DECF + (size_t)98304*2)               // half[4096]   out1 B-frags
#define OFF_WF    (OFF_OUT1F + (size_t)4096*2)               // half[61440]  enc B-frags

// ================= prep: fuse attn+out1, pack all weights into MFMA frag order =================
__global__ void prep_kernel(const float* attn_W, const float* attn_b,
                            const float* dec_Wih, const float* dec_Whh,
                            const float* out1_W, const float* out1_b,
                            const float* enc_Wih, const float* enc_Whh,
                            __half* attnF, float* attnB, __half* decF, __half* out1F, __half* Wf) {
  int i = blockIdx.x * 256 + threadIdx.x;
  if (i < 65536) {
    // fused A~[s][h] frags: idx = ((w*4+st)*4+kb)*512 + l*8 + e
    int e = i & 7, l = (i >> 3) & 63, kb = (i >> 9) & 3, st = (i >> 11) & 3, w = i >> 13;
    int h = kb*32 + ((l >> 4) << 3) + e;
    int s = w*64 + st*16 + (l & 15);
    float acc = attn_W[s*160 + h];
    #pragma unroll 8
    for (int f = 0; f < 32; ++f) acc += out1_W[f*128 + h] * attn_W[s*160 + 128 + f];
    attnF[i] = __float2half(acc);
    return;
  }
  i -= 65536;
  if (i < 512) {               // b~[s] = attn_b[s] + sum_f out1_b[f]*A_y[s][f]
    float acc = attn_b[i];
    #pragma unroll 8
    for (int f = 0; f < 32; ++f) acc += out1_b[f] * attn_W[i*160 + 128 + f];
    attnB[i] = acc;
    return;
  }
  i -= 512;
  if (i < 98304) {
    int e = i & 7, l = (i >> 3) & 63, fi = (i >> 9) % 48, w = i / 24576;
    int lq = l >> 4, l15 = l & 15;
    float val;
    if (fi < 32) {            // r/z combined [ctx|h] K=256
      int g2 = fi >> 4, sub = (fi >> 3) & 1, kb = fi & 7;
      int k = kb*32 + lq*8 + e, j = w*32 + sub*16 + l15, jg = g2*128 + j;
      val = (k < 128) ? dec_Wih[jg*128 + k] : dec_Whh[jg*128 + (k - 128)];
    } else {                  // nh (Whh) then ni (Wih), K=128 each
      int f2 = fi - 32, cat = f2 >> 3, sub = (f2 >> 2) & 1, kb4 = f2 & 3;
      int k = kb4*32 + lq*8 + e, j = 256 + w*32 + sub*16 + l15;
      val = cat ? dec_Wih[j*128 + k] : dec_Whh[j*128 + k];
    }
    decF[i] = __float2half(val);
    return;
  }
  i -= 98304;
  if (i < 4096) {             // out1F frags: tile(2) x kb(4) x lane x e
    int e = i & 7, l = (i >> 3) & 63, kb = (i >> 9) & 3, tile = (i >> 11) & 1;
    int k = kb*32 + ((l >> 4) << 3) + e;
    int f = tile*16 + (l & 15);
    out1F[i] = __float2half(out1_W[f*128 + k]);
    return;
  }
  i -= 4096;
  if (i < 61440) {
    int e = i & 7, l = (i >> 3) & 63, q = i >> 9;
    int kb = q % 5, tt = (q / 5) % 6, w = q / 30;
    int g = tt >> 1, sub = tt & 1;
    int k = kb*32 + ((l >> 4) << 3) + e;
    int J = g*128 + w*32 + sub*16 + (l & 15);
    float v = (k < 128) ? enc_Whh[J*128 + k] : enc_Wih[J*32 + (k - 128)];
    Wf[i] = __float2half(v);
  }
}

// ================= encoder: MFMA, 8 batches/block, 8 waves (2/SIMD), 1 barrier/step =================
#define HXS 168

__global__ void __launch_bounds__(512, 1) enc_kernel(
    const float* __restrict__ xb, const __half* __restrict__ Wf,
    const float* __restrict__ bih, const float* __restrict__ bhh,
    __half* __restrict__ enc_out, float* __restrict__ hfin) {
  __shared__ __align__(16) _Float16 hx[2][16][HXS];   // rows 0..7 live, 8..15 zero
  const int tid  = threadIdx.x;
  const int lane = tid & 63, wid = tid >> 6;          // 8 waves
  const int l15  = lane & 15, lq = lane >> 4;
  const int b0   = blockIdx.x * 8;
  const int ow   = wid >> 1, sub = wid & 1;           // old-wave / col-sub for Wf indexing
  const int j    = wid*16 + l15;                      // this wave's gate col

  half8 Bfr[5], Bfz[5], Bfn[5];
  { const half8* wfp = (const half8*)Wf;
    #pragma unroll
    for (int kb = 0; kb < 5; ++kb) {
      Bfr[kb] = wfp[((ow*6 + sub)*5     + kb)*64 + lane];
      Bfz[kb] = wfp[((ow*6 + 2 + sub)*5 + kb)*64 + lane];
      Bfn[kb] = wfp[((ow*6 + 4 + sub)*5 + kb)*64 + lane];
    }
  }
  const float br  = bih[j]       + bhh[j];
  const float bz  = bih[128 + j] + bhh[128 + j];
  const float bnh = bhh[256 + j];
  const float bni = bih[256 + j];
  float hreg[4] = {0.f, 0.f, 0.f, 0.f};

  const int m2 = (tid >> 5) & 7, c2 = tid & 31;   // x staging roles (tid<256): 8 rows x 32 cols

  for (int i = tid; i < 2*16*HXS; i += 512) (&hx[0][0][0])[i] = (_Float16)0.f;
  __syncthreads();
  if (tid < 256) hx[0][m2][128 + c2] = (_Float16)xb[((size_t)(b0 + m2)*512 + 0)*32 + c2];
  __syncthreads();

  int p = 0;
  for (int t = 0; t < 512; ++t) {
    const int tn = (t < 511) ? t + 1 : 511;
    float xpre = 0.f;
    if (tid < 256) xpre = xb[((size_t)(b0 + m2)*512 + tn)*32 + c2];

    half8 A[5];
    #pragma unroll
    for (int kb = 0; kb < 5; ++kb)
      A[kb] = *(const half8*)&hx[p][l15][kb*32 + lq*8];

    f32x4 Cr = {0.f,0.f,0.f,0.f}, Cz = {0.f,0.f,0.f,0.f};
    f32x4 Cnh = {0.f,0.f,0.f,0.f}, Cni = {0.f,0.f,0.f,0.f};
    #pragma unroll
    for (int kb = 0; kb < 5; ++kb) {
      Cr = __builtin_amdgcn_mfma_f32_16x16x32_f16(A[kb], Bfr[kb], Cr, 0, 0, 0);
      Cz = __builtin_amdgcn_mfma_f32_16x16x32_f16(A[kb], Bfz[kb], Cz, 0, 0, 0);
    }
    #pragma unroll
    for (int kb = 0; kb < 4; ++kb)
      Cnh = __builtin_amdgcn_mfma_f32_16x16x32_f16(A[kb], Bfn[kb], Cnh, 0, 0, 0);
    Cni = __builtin_amdgcn_mfma_f32_16x16x32_f16(A[4], Bfn[4], Cni, 0, 0, 0);

    // gates (4 evals/lane), write into the other buffer
    #pragma unroll
    for (int i = 0; i < 4; ++i) {
      float xr = Cr[i] + br;
      float xz = Cz[i] + bz;
      float r = __builtin_amdgcn_rcpf(1.f + __builtin_amdgcn_exp2f(-LOG2E*xr));
      float z = __builtin_amdgcn_rcpf(1.f + __builtin_amdgcn_exp2f(-LOG2E*xz));
      float narg = (Cni[i] + bni) + r * (Cnh[i] + bnh);
      float n = 1.f - 2.f*__builtin_amdgcn_rcpf(__builtin_amdgcn_exp2f((2.f*LOG2E)*narg) + 1.f);
      float hnew = n + z*(hreg[i] - n);
      hreg[i] = hnew;
      if (lq < 2)
        hx[p ^ 1][4*lq + i][j] = (_Float16)hnew;
    }
    if (tid < 256) hx[p ^ 1][m2][128 + c2] = (_Float16)xpre;
    __syncthreads();   // single barrier per step

    { half2v hv = *(const half2v*)&hx[p ^ 1][wid][lane*2];
      *(half2v*)((void*)&enc_out[((size_t)(b0 + wid)*512 + t)*128 + lane*2]) = hv; }
    p ^= 1;
  }

  if (lq < 2)
    #pragma unroll
    for (int i = 0; i < 4; ++i)
      hfin[(size_t)(b0 + 4*lq + i)*128 + j] = hreg[i];
}

// ================= decoder: 4 barriers/step, fused-attn, GRU prefetch, batched epilogue =================
struct DecSmem {
  _Float16 ET[128*512];   // 128 KB, swizzled: (h,s) -> h*512 + ((s>>3 ^ (h&7) ^ ((h>>3)&7))<<3) + (s&7)
  _Float16 wsm[512];      // softmax weights fp16
  float hsm[128];         // h fp32 (gate carry)
  _Float16 hh[128];       // h fp16 (P1 A operand)
  _Float16 cxh[2][256];   // ping-pong [ctx | h]
  _Float16 hist[TO*128];  // h history for out epilogue
  float red[16];
  float d32[32];          // y0 - out1(h0)
};

__global__ void __launch_bounds__(512, 2) dec_kernel(const float* __restrict__ xb,
    const __half* __restrict__ enc_out, const float* __restrict__ hfin,
    const __half* __restrict__ attnF, const float* __restrict__ attnB,
    const float* __restrict__ attn_W,
    const __half* __restrict__ decF, const __half* __restrict__ out1F,
    const float* __restrict__ dbih, const float* __restrict__ dbhh,
    const float* __restrict__ out1_W, const float* __restrict__ out1_b,
    const float* __restrict__ out2_W, const float* __restrict__ out2_b,
    float* __restrict__ out) {
  __shared__ __align__(16) DecSmem sm;
  const int tid = threadIdx.x, lane = tid & 63, wid = tid >> 6;
  const int l15 = lane & 15, lq = lane >> 4;
  const int b = blockIdx.x;

  const half8* aFp = (const half8*)attnF;
  const half8* dFp = (const half8*)decF;
  const half8* oFp = (const half8*)out1F;
  const int Wb = wid >> 1, sb = wid & 1;

  // ---- per-thread scalar params ----
  const float ab = attnB[tid];                       // fused logit bias for s = tid
  const int jg = wid*16 + l15;                       // this wave's gate col
  const float bR  = dbih[jg]       + dbhh[jg];
  const float bZ  = dbih[128 + jg] + dbhh[128 + jg];
  const float bNH = dbhh[256 + jg];
  const float bNI = dbih[256 + jg];
  const float o1b0 = out1_b[l15], o1b1 = out1_b[16 + l15];
  const float o2w0 = out2_W[l15], o2w1 = out2_W[16 + l15];
  const float o2b  = out2_b[0];

  // ---- staging: E transposed+swizzled into LDS; h0; step-0 logit correction ----
  { const half8* src = (const half8*)(enc_out + (size_t)b*512*128);
    for (int i = tid; i < 8192; i += 512) {
      half8 v = src[i];
      int s = i >> 4, h0 = (i & 15) * 8, sg = s >> 3, s7 = s & 7;
      #pragma unroll
      for (int j = 0; j < 8; ++j) {
        int h = h0 + j;
        sm.ET[h*512 + (((sg ^ (h & 7) ^ ((h >> 3) & 7)) << 3)) + s7] = v[j];
      }
    } }
  if (tid < 128) { float hv = hfin[(size_t)b*128 + tid];
    sm.hsm[tid] = hv; sm.hh[tid] = (_Float16)hv; sm.cxh[0][128 + tid] = (_Float16)hv; }
  if (tid < 32) {
    // d32 = y0 - out1(h0)   (exact fp32)
    float o1v = out1_b[tid];
    for (int h = 0; h < 128; ++h) o1v += out1_W[tid*128 + h] * hfin[(size_t)b*128 + h];
    sm.d32[tid] = xb[((size_t)b*512 + 511)*32 + tid] - o1v;
  }
  __syncthreads();
  float c0reg = 0.f;     // per-thread (s = tid) step-0 correction
  #pragma unroll 8
  for (int f = 0; f < 32; ++f) c0reg += sm.d32[f] * attn_W[tid*160 + 128 + f];

  const half8 Az = {};
  const int hrow = wid*16 + l15;                     // P3 B-operand row
  const int hswz = (hrow & 7) ^ ((hrow >> 3) & 7);   // its swizzle key

  for (int tt = 0; tt < TO; ++tt) {
    _Float16* cxhR = sm.cxh[tt & 1];         // read buffer (ctx_t | h_{t-1})
    _Float16* cxhW = sm.cxh[(tt & 1) ^ 1];   // write buffer (h_t)

    // ---- prefetch GRU B-frags (consumed in P4; latency hidden under P1-P3) ----
    half8 BrzR[8], BrzZ[8], Bnh4[4], Bni4[4];
    #pragma unroll
    for (int kb = 0; kb < 8; ++kb) {
      BrzR[kb] = dFp[(Wb*48 +      sb*8 + kb)*64 + lane];
      BrzZ[kb] = dFp[(Wb*48 + 16 + sb*8 + kb)*64 + lane];
    }
    #pragma unroll
    for (int kb = 0; kb < 4; ++kb) {
      Bnh4[kb] = dFp[(Wb*48 + 32 + sb*4 + kb)*64 + lane];
      Bni4[kb] = dFp[(Wb*48 + 40 + sb*4 + kb)*64 + lane];
    }

    // ---- P1: fused logits MFMA (K=128) + wave softmax partials ----
    half8 A[4];
    #pragma unroll
    for (int kb = 0; kb < 4; ++kb)
      A[kb] = (l15 == 0) ? *(const half8*)&sm.hh[kb*32 + lq*8] : Az;
    f32x4 CL[4];
    #pragma unroll
    for (int stt = 0; stt < 4; ++stt) CL[stt] = (f32x4){0.f,0.f,0.f,0.f};
    #pragma unroll
    for (int stt = 0; stt < 4; ++stt)
      #pragma unroll
      for (int kb = 0; kb < 4; ++kb)
        CL[stt] = __builtin_amdgcn_mfma_f32_16x16x32_f16(
            A[kb], aFp[((wid*4 + stt)*4 + kb)*64 + lane], CL[stt], 0, 0, 0);
    // redistribute: thread tid gets logit s = tid  (s = wid*64 + lq*16 + l15)
    float t0 = __shfl(CL[0][0], l15), t1 = __shfl(CL[1][0], l15);
    float t2 = __shfl(CL[2][0], l15), t3 = __shfl(CL[3][0], l15);
    float v = (lq == 0) ? t0 : (lq == 1) ? t1 : (lq == 2) ? t2 : t3;
    v += ab;
    if (tt == 0) v += c0reg;
    float mw = v;
    #pragma unroll
    for (int off = 1; off < 64; off <<= 1) mw = fmaxf(mw, __shfl_xor(mw, off));
    float sw = __builtin_amdgcn_exp2f(LOG2E*(v - mw));
    #pragma unroll
    for (int off = 1; off < 64; off <<= 1) sw += __shfl_xor(sw, off);
    if (lane == 0) { sm.red[wid] = mw; sm.red[8 + wid] = sw; }
    __syncthreads();  // B1

    // ---- P2: softmax finalize, write w fp16 ----
    float M = sm.red[0];
    #pragma unroll
    for (int g = 1; g < 8; ++g) M = fmaxf(M, sm.red[g]);
    float tot = 0.f;
    #pragma unroll
    for (int g = 0; g < 8; ++g) tot += sm.red[8 + g] * __builtin_amdgcn_exp2f(LOG2E*(sm.red[g] - M));
    float wv = __builtin_amdgcn_exp2f(LOG2E*(v - M)) * __builtin_amdgcn_rcpf(tot);
    sm.wsm[tid] = (_Float16)wv;
    __syncthreads();  // B2

    // ---- P3: ctx = w @ E via MFMA, swizzled ET reads ----
    f32x4 Ca[2];
    Ca[0] = (f32x4){0.f,0.f,0.f,0.f}; Ca[1] = (f32x4){0.f,0.f,0.f,0.f};
    #pragma unroll
    for (int kb = 0; kb < 16; ++kb) {
      const half8 bet = *(const half8*)&sm.ET[hrow*512 + (((kb*4 + lq) ^ hswz) << 3)];
      const half8 aw  = (l15 == 0) ? *(const half8*)&sm.wsm[kb*32 + lq*8] : Az;
      Ca[kb & 1] = __builtin_amdgcn_mfma_f32_16x16x32_f16(aw, bet, Ca[kb & 1], 0, 0, 0);
    }
    if (lane < 16)
      cxhR[wid*16 + l15] = (_Float16)(Ca[0][0] + Ca[1][0]);
    __syncthreads();  // B3

    // ---- P4: GRU MFMA (prefetched B) + in-register gates ----
    half8 Ag[8];
    #pragma unroll
    for (int kb = 0; kb < 8; ++kb)
      Ag[kb] = (l15 == 0) ? *(const half8*)&cxhR[kb*32 + lq*8] : Az;
    f32x4 Cr, Cz, Cnh4, Cni4;
    Cr = (f32x4){0.f,0.f,0.f,0.f}; Cz = (f32x4){0.f,0.f,0.f,0.f};
    Cnh4 = (f32x4){0.f,0.f,0.f,0.f}; Cni4 = (f32x4){0.f,0.f,0.f,0.f};
    #pragma unroll
    for (int kb = 0; kb < 8; ++kb) {
      Cr = __builtin_amdgcn_mfma_f32_16x16x32_f16(Ag[kb], BrzR[kb], Cr, 0, 0, 0);
      Cz = __builtin_amdgcn_mfma_f32_16x16x32_f16(Ag[kb], BrzZ[kb], Cz, 0, 0, 0);
    }
    #pragma unroll
    for (int kb = 0; kb < 4; ++kb) {
      Cnh4 = __builtin_amdgcn_mfma_f32_16x16x32_f16(Ag[4 + kb], Bnh4[kb], Cnh4, 0, 0, 0);
      Cni4 = __builtin_amdgcn_mfma_f32_16x16x32_f16(Ag[kb],     Bni4[kb], Cni4, 0, 0, 0);
    }
    if (lane < 16) {
      float xr = Cr[0] + bR, xz = Cz[0] + bZ;
      float r = __builtin_amdgcn_rcpf(1.f + __builtin_amdgcn_exp2f(-LOG2E*xr));
      float z = __builtin_amdgcn_rcpf(1.f + __builtin_amdgcn_exp2f(-LOG2E*xz));
      float narg = (Cni4[0] + bNI) + r * (Cnh4[0] + bNH);
      float n = 1.f - 2.f*__builtin_amdgcn_rcpf(__builtin_amdgcn_exp2f((2.f*LOG2E)*narg) + 1.f);
      float hnew = n + z*(sm.hsm[jg] - n);
      sm.hsm[jg] = hnew;
      _Float16 hf = (_Float16)hnew;
      sm.hh[jg] = hf;                      // next P1 A (after B4)
      cxhW[128 + jg] = hf;                 // next P4 A
      sm.hist[tt*128 + jg] = hf;           // epilogue
    }
    __syncthreads();  // B4
  }

  // ---- epilogue: out1+out2 for all 24 steps, wave 0, batched M=16 MFMA ----
  if (wid == 0) {
    #pragma unroll
    for (int chunk = 0; chunk < 2; ++chunk) {
      half8 Ae[4];
      #pragma unroll
      for (int kb = 0; kb < 4; ++kb) {
        int step = chunk*16 + l15;
        Ae[kb] = (step < TO) ? *(const half8*)&sm.hist[step*128 + kb*32 + lq*8] : Az;
      }
      f32x4 C0, C1;
      C0 = (f32x4){0.f,0.f,0.f,0.f}; C1 = (f32x4){0.f,0.f,0.f,0.f};
      #pragma unroll
      for (int kb = 0; kb < 4; ++kb) {
        C0 = __builtin_amdgcn_mfma_f32_16x16x32_f16(Ae[kb], oFp[kb*64 + lane],       C0, 0, 0, 0);
        C1 = __builtin_amdgcn_mfma_f32_16x16x32_f16(Ae[kb], oFp[(4 + kb)*64 + lane], C1, 0, 0, 0);
      }
      #pragma unroll
      for (int i = 0; i < 4; ++i) {
        int row = lq*4 + i, step = chunk*16 + row;
        float y0 = C0[i] + o1b0, y1 = C1[i] + o1b1;
        float part = fmaxf(y0, 0.f)*o2w0 + fmaxf(y1, 0.f)*o2w1;
        #pragma unroll
        for (int off = 1; off < 16; off <<= 1) part += __shfl_xor(part, off, 16);
        if (l15 == 0 && step < TO)
          out[(size_t)b*TO + step] = fmaxf(part + o2b, 0.f);
      }
    }
  }
}

extern "C" void kernel_launch(void* const* d_in, const int* in_sizes, int n_in,
                              void* d_out, int out_size, void* d_ws, size_t ws_size,
                              hipStream_t stream) {
  const float* xb      = (const float*)d_in[0];
  const float* enc_Wih = (const float*)d_in[1];
  const float* enc_Whh = (const float*)d_in[2];
  const float* enc_bih = (const float*)d_in[3];
  const float* enc_bhh = (const float*)d_in[4];
  const float* attn_W  = (const float*)d_in[5];
  const float* attn_b  = (const float*)d_in[6];
  const float* dec_Wih = (const float*)d_in[7];
  const float* dec_Whh = (const float*)d_in[8];
  const float* dec_bih = (const float*)d_in[9];
  const float* dec_bhh = (const float*)d_in[10];
  const float* out1_W  = (const float*)d_in[11];
  const float* out1_b  = (const float*)d_in[12];
  const float* out2_W  = (const float*)d_in[13];
  const float* out2_b  = (const float*)d_in[14];

  char* ws = (char*)d_ws;
  __half* enc_out = (__half*)(ws + OFF_ENCOUT);
  float*  hfin    = (float*)(ws + OFF_HFIN);
  __half* attnF   = (__half*)(ws + OFF_ATTNF);
  float*  attnB   = (float*)(ws + OFF_ATTNB);
  __half* decF    = (__half*)(ws + OFF_DECF);
  __half* out1F   = (__half*)(ws + OFF_OUT1F);
  __half* Wf      = (__half*)(ws + OFF_WF);

  prep_kernel<<<900, 256, 0, stream>>>(attn_W, attn_b, dec_Wih, dec_Whh, out1_W, out1_b,
                                       enc_Wih, enc_Whh, attnF, attnB, decF, out1F, Wf);
  enc_kernel<<<256, 512, 0, stream>>>(xb, Wf, enc_bih, enc_bhh, enc_out, hfin);
  dec_kernel<<<2048, 512, 0, stream>>>(xb, enc_out, hfin, attnF, attnB, attn_W, decF, out1F,
                                       dec_bih, dec_bhh, out1_W, out1_b, out2_W, out2_b,
                                       (float*)d_out);
}

// Round 13
// 1107.020 us; speedup vs baseline: 1.0533x; 1.0533x over previous
//
#include <hip/hip_runtime.h>
#include <hip/hip_fp16.h>

#define BB 2048
#define SS 512
#define FF 32
#define HH 128
#define TO 24
#define LOG2E 1.4426950408889634f

typedef unsigned int uint;
using half4 = __attribute__((ext_vector_type(4))) _Float16;
using half8 = __attribute__((ext_vector_type(8))) _Float16;
using f32x4 = __attribute__((ext_vector_type(4))) float;

// ---- workspace layout (bytes) ----
#define OFF_ENCOUT 0ull                                      // half[B][S][H]
#define OFF_HFIN  (OFF_ENCOUT + (size_t)BB*SS*HH*2)          // float[B][H]
#define OFF_ATTNF (OFF_HFIN + (size_t)BB*HH*4)               // half[65536]  fused logits B-frags (K=128)
#define OFF_ATTNB (OFF_ATTNF + (size_t)65536*2)              // float[512]   fused logit bias
#define OFF_DECF  (OFF_ATTNB + (size_t)512*4)                // half[98304]  GRU B-frags
#define OFF_OUT1F (OFF_DECF + (size_t)98304*2)               // half[4096]   out1 B-frags
#define OFF_WF    (OFF_OUT1F + (size_t)4096*2)               // half[61440]  enc B-frags

// ================= prep: fuse attn+out1, pack all weights into MFMA frag order =================
__global__ void prep_kernel(const float* attn_W, const float* attn_b,
                            const float* dec_Wih, const float* dec_Whh,
                            const float* out1_W, const float* out1_b,
                            const float* enc_Wih, const float* enc_Whh,
                            __half* attnF, float* attnB, __half* decF, __half* out1F, __half* Wf) {
  int i = blockIdx.x * 256 + threadIdx.x;
  if (i < 65536) {
    // fused A~[s][h] frags: idx = ((w*4+st)*4+kb)*512 + l*8 + e
    int e = i & 7, l = (i >> 3) & 63, kb = (i >> 9) & 3, st = (i >> 11) & 3, w = i >> 13;
    int h = kb*32 + ((l >> 4) << 3) + e;
    int s = w*64 + st*16 + (l & 15);
    float acc = attn_W[s*160 + h];
    #pragma unroll 8
    for (int f = 0; f < 32; ++f) acc += out1_W[f*128 + h] * attn_W[s*160 + 128 + f];
    attnF[i] = __float2half(acc);
    return;
  }
  i -= 65536;
  if (i < 512) {               // b~[s] = attn_b[s] + sum_f out1_b[f]*A_y[s][f]
    float acc = attn_b[i];
    #pragma unroll 8
    for (int f = 0; f < 32; ++f) acc += out1_b[f] * attn_W[i*160 + 128 + f];
    attnB[i] = acc;
    return;
  }
  i -= 512;
  if (i < 98304) {
    int e = i & 7, l = (i >> 3) & 63, fi = (i >> 9) % 48, w = i / 24576;
    int lq = l >> 4, l15 = l & 15;
    float val;
    if (fi < 32) {            // r/z combined [ctx|h] K=256
      int g2 = fi >> 4, sub = (fi >> 3) & 1, kb = fi & 7;
      int k = kb*32 + lq*8 + e, j = w*32 + sub*16 + l15, jg = g2*128 + j;
      val = (k < 128) ? dec_Wih[jg*128 + k] : dec_Whh[jg*128 + (k - 128)];
    } else {                  // nh (Whh) then ni (Wih), K=128 each
      int f2 = fi - 32, cat = f2 >> 3, sub = (f2 >> 2) & 1, kb4 = f2 & 3;
      int k = kb4*32 + lq*8 + e, j = 256 + w*32 + sub*16 + l15;
      val = cat ? dec_Wih[j*128 + k] : dec_Whh[j*128 + k];
    }
    decF[i] = __float2half(val);
    return;
  }
  i -= 98304;
  if (i < 4096) {             // out1F frags: tile(2) x kb(4) x lane x e
    int e = i & 7, l = (i >> 3) & 63, kb = (i >> 9) & 3, tile = (i >> 11) & 1;
    int k = kb*32 + ((l >> 4) << 3) + e;
    int f = tile*16 + (l & 15);
    out1F[i] = __float2half(out1_W[f*128 + k]);
    return;
  }
  i -= 4096;
  if (i < 61440) {
    int e = i & 7, l = (i >> 3) & 63, q = i >> 9;
    int kb = q % 5, tt = (q / 5) % 6, w = q / 30;
    int g = tt >> 1, sub = tt & 1;
    int k = kb*32 + ((l >> 4) << 3) + e;
    int J = g*128 + w*32 + sub*16 + (l & 15);
    float v = (k < 128) ? enc_Whh[J*128 + k] : enc_Wih[J*32 + (k - 128)];
    Wf[i] = __float2half(v);
  }
}

// ================= encoder: MFMA, 8 batches/block, ping-pong hx, 1 barrier/step,
//                   2-deep x register pipeline =================
#define HXS 168

__global__ void __launch_bounds__(256, 1) enc_kernel(
    const float* __restrict__ xb, const __half* __restrict__ Wf,
    const float* __restrict__ bih, const float* __restrict__ bhh,
    __half* __restrict__ enc_out, float* __restrict__ hfin) {
  __shared__ __align__(16) _Float16 hx[2][16][HXS];   // rows 0..7 live, 8..15 zero
  const int tid  = threadIdx.x;
  const int lane = tid & 63, wid = tid >> 6;
  const int l15  = lane & 15, lq = lane >> 4;
  const int b0   = blockIdx.x * 8;

  half8 Bf[6][5];
  { const half8* wfp = (const half8*)Wf;
    #pragma unroll
    for (int tt = 0; tt < 6; ++tt)
      #pragma unroll
      for (int kb = 0; kb < 5; ++kb)
        Bf[tt][kb] = wfp[((wid*6 + tt)*5 + kb)*64 + lane];
  }

  float br[2], bz[2], bnh[2], bni[2];
  #pragma unroll
  for (int sub = 0; sub < 2; ++sub) {
    int j = wid*32 + sub*16 + l15;
    br[sub]  = bih[j]       + bhh[j];
    bz[sub]  = bih[128 + j] + bhh[128 + j];
    bnh[sub] = bhh[256 + j];
    bni[sub] = bih[256 + j];
  }
  float hreg[2][4] = {{0.f,0.f,0.f,0.f},{0.f,0.f,0.f,0.f}};

  const int m2 = tid >> 5, c2 = tid & 31;   // staging: 8 rows x 32 cols
  const float* xbase = xb + ((size_t)(b0 + m2)*512)*32 + c2;

  for (int i = tid; i < 2*16*HXS; i += 256) (&hx[0][0][0])[i] = (_Float16)0.f;
  __syncthreads();
  hx[0][m2][128 + c2] = (_Float16)xbase[0];
  __syncthreads();

  float xq_next = xbase[1*32];    // x_{t+1} (pipeline register, 1 iter of cover min)

  int p = 0;
  for (int t = 0; t < 512; ++t) {
    // issue load for x_{t+2} now; consume x_{t+1} (loaded last iteration) at step end
    const int tn2 = (t < 510) ? t + 2 : 511;
    float xq_new = xbase[(size_t)tn2*32];

    half8 A[5];
    #pragma unroll
    for (int kb = 0; kb < 5; ++kb)
      A[kb] = *(const half8*)&hx[p][l15][kb*32 + lq*8];

    f32x4 Cr[2], Cz[2], Cnh[2], Cni[2];
    #pragma unroll
    for (int sub = 0; sub < 2; ++sub) {
      Cr[sub] = (f32x4){0.f,0.f,0.f,0.f};
      Cz[sub] = (f32x4){0.f,0.f,0.f,0.f};
      Cnh[sub] = (f32x4){0.f,0.f,0.f,0.f};
      Cni[sub] = (f32x4){0.f,0.f,0.f,0.f};
    }
    #pragma unroll
    for (int sub = 0; sub < 2; ++sub) {
      #pragma unroll
      for (int kb = 0; kb < 5; ++kb) {
        Cr[sub] = __builtin_amdgcn_mfma_f32_16x16x32_f16(A[kb], Bf[sub][kb],     Cr[sub], 0, 0, 0);
        Cz[sub] = __builtin_amdgcn_mfma_f32_16x16x32_f16(A[kb], Bf[2 + sub][kb], Cz[sub], 0, 0, 0);
      }
      #pragma unroll
      for (int kb = 0; kb < 4; ++kb)
        Cnh[sub] = __builtin_amdgcn_mfma_f32_16x16x32_f16(A[kb], Bf[4 + sub][kb], Cnh[sub], 0, 0, 0);
      Cni[sub] = __builtin_amdgcn_mfma_f32_16x16x32_f16(A[4], Bf[4 + sub][4], Cni[sub], 0, 0, 0);
    }

    // gates: write h_t and x_{t+1} into the OTHER buffer (no barrier needed before)
    #pragma unroll
    for (int sub = 0; sub < 2; ++sub)
      #pragma unroll
      for (int i = 0; i < 4; ++i) {
        float xr = Cr[sub][i] + br[sub];
        float xz = Cz[sub][i] + bz[sub];
        float r = __builtin_amdgcn_rcpf(1.f + __builtin_amdgcn_exp2f(-LOG2E*xr));
        float z = __builtin_amdgcn_rcpf(1.f + __builtin_amdgcn_exp2f(-LOG2E*xz));
        float narg = (Cni[sub][i] + bni[sub]) + r * (Cnh[sub][i] + bnh[sub]);
        float n = 1.f - 2.f*__builtin_amdgcn_rcpf(__builtin_amdgcn_exp2f((2.f*LOG2E)*narg) + 1.f);
        float hnew = n + z*(hreg[sub][i] - n);
        hreg[sub][i] = hnew;
        if (lq < 2)
          hx[p ^ 1][4*lq + i][wid*32 + sub*16 + l15] = (_Float16)hnew;
      }
    hx[p ^ 1][m2][128 + c2] = (_Float16)xq_next;   // x_{t+1}, loaded one full iter ago
    xq_next = xq_new;
    __syncthreads();   // single barrier per step

    { half4 hv = *(const half4*)&hx[p ^ 1][m2][c2*4];
      *(half4*)((void*)&enc_out[((size_t)(b0 + m2)*512 + t)*128 + c2*4]) = hv; }
    p ^= 1;
  }

  if (lq < 2)
    #pragma unroll
    for (int sub = 0; sub < 2; ++sub)
      #pragma unroll
      for (int i = 0; i < 4; ++i)
        hfin[(size_t)(b0 + 4*lq + i)*128 + wid*32 + sub*16 + l15] = hreg[sub][i];
}

// ================= decoder: 4 barriers/step, fused-attn, batched out epilogue =================
struct DecSmem {
  _Float16 ET[128*512];   // 128 KB, swizzled: (h,s) -> h*512 + ((s>>3 ^ (h&7) ^ ((h>>3)&7))<<3) + (s&7)
  _Float16 wsm[512];      // softmax weights fp16
  float hsm[128];         // h fp32 (gate carry)
  _Float16 hh[128];       // h fp16 (P1 A operand)
  _Float16 cxh[2][256];   // ping-pong [ctx | h]
  _Float16 hist[TO*128];  // h history for out epilogue
  float red[16];
  float d32[32];          // y0 - out1(h0)
};

__global__ void __launch_bounds__(512, 2) dec_kernel(const float* __restrict__ xb,
    const __half* __restrict__ enc_out, const float* __restrict__ hfin,
    const __half* __restrict__ attnF, const float* __restrict__ attnB,
    const float* __restrict__ attn_W,
    const __half* __restrict__ decF, const __half* __restrict__ out1F,
    const float* __restrict__ dbih, const float* __restrict__ dbhh,
    const float* __restrict__ out1_W, const float* __restrict__ out1_b,
    const float* __restrict__ out2_W, const float* __restrict__ out2_b,
    float* __restrict__ out) {
  __shared__ __align__(16) DecSmem sm;
  const int tid = threadIdx.x, lane = tid & 63, wid = tid >> 6;
  const int l15 = lane & 15, lq = lane >> 4;
  const int b = blockIdx.x;

  const half8* aFp = (const half8*)attnF;
  const half8* dFp = (const half8*)decF;
  const half8* oFp = (const half8*)out1F;
  const int Wb = wid >> 1, sb = wid & 1;

  // ---- per-thread scalar params ----
  const float ab = attnB[tid];                       // fused logit bias for s = tid
  const int jg = wid*16 + l15;                       // this wave's gate col
  const float bR  = dbih[jg]       + dbhh[jg];
  const float bZ  = dbih[128 + jg] + dbhh[128 + jg];
  const float bNH = dbhh[256 + jg];
  const float bNI = dbih[256 + jg];
  const float o1b0 = out1_b[l15], o1b1 = out1_b[16 + l15];
  const float o2w0 = out2_W[l15], o2w1 = out2_W[16 + l15];
  const float o2b  = out2_b[0];

  // ---- staging: E transposed+swizzled into LDS; h0; step-0 logit correction ----
  { const half8* src = (const half8*)(enc_out + (size_t)b*512*128);
    for (int i = tid; i < 8192; i += 512) {
      half8 v = src[i];
      int s = i >> 4, h0 = (i & 15) * 8, sg = s >> 3, s7 = s & 7;
      #pragma unroll
      for (int j = 0; j < 8; ++j) {
        int h = h0 + j;
        sm.ET[h*512 + (((sg ^ (h & 7) ^ ((h >> 3) & 7)) << 3)) + s7] = v[j];
      }
    } }
  if (tid < 128) { float hv = hfin[(size_t)b*128 + tid];
    sm.hsm[tid] = hv; sm.hh[tid] = (_Float16)hv; sm.cxh[0][128 + tid] = (_Float16)hv; }
  if (tid < 32) {
    // d32 = y0 - out1(h0)   (exact fp32)
    float o1v = out1_b[tid];
    for (int h = 0; h < 128; ++h) o1v += out1_W[tid*128 + h] * hfin[(size_t)b*128 + h];
    sm.d32[tid] = xb[((size_t)b*512 + 511)*32 + tid] - o1v;
  }
  __syncthreads();
  float c0reg = 0.f;     // per-thread (s = tid) step-0 correction
  #pragma unroll 8
  for (int f = 0; f < 32; ++f) c0reg += sm.d32[f] * attn_W[tid*160 + 128 + f];

  const half8 Az = {};
  const int hrow = wid*16 + l15;                     // P3 B-operand row
  const int hswz = (hrow & 7) ^ ((hrow >> 3) & 7);   // its swizzle key

  for (int tt = 0; tt < TO; ++tt) {
    _Float16* cxhR = sm.cxh[tt & 1];         // read buffer (ctx_t | h_{t-1})
    _Float16* cxhW = sm.cxh[(tt & 1) ^ 1];   // write buffer (h_t)

    // ---- P1: fused logits MFMA (K=128) + wave softmax partials ----
    half8 A[4];
    #pragma unroll
    for (int kb = 0; kb < 4; ++kb)
      A[kb] = (l15 == 0) ? *(const half8*)&sm.hh[kb*32 + lq*8] : Az;
    f32x4 CL[4];
    #pragma unroll
    for (int stt = 0; stt < 4; ++stt) CL[stt] = (f32x4){0.f,0.f,0.f,0.f};
    #pragma unroll
    for (int stt = 0; stt < 4; ++stt)
      #pragma unroll
      for (int kb = 0; kb < 4; ++kb)
        CL[stt] = __builtin_amdgcn_mfma_f32_16x16x32_f16(
            A[kb], aFp[((wid*4 + stt)*4 + kb)*64 + lane], CL[stt], 0, 0, 0);
    // redistribute: thread tid gets logit s = tid  (s = wid*64 + lq*16 + l15)
    float t0 = __shfl(CL[0][0], l15), t1 = __shfl(CL[1][0], l15);
    float t2 = __shfl(CL[2][0], l15), t3 = __shfl(CL[3][0], l15);
    float v = (lq == 0) ? t0 : (lq == 1) ? t1 : (lq == 2) ? t2 : t3;
    v += ab;
    if (tt == 0) v += c0reg;
    float mw = v;
    #pragma unroll
    for (int off = 1; off < 64; off <<= 1) mw = fmaxf(mw, __shfl_xor(mw, off));
    float sw = __builtin_amdgcn_exp2f(LOG2E*(v - mw));
    #pragma unroll
    for (int off = 1; off < 64; off <<= 1) sw += __shfl_xor(sw, off);
    if (lane == 0) { sm.red[wid] = mw; sm.red[8 + wid] = sw; }
    __syncthreads();  // B1

    // ---- P2: softmax finalize, write w fp16 ----
    float M = sm.red[0];
    #pragma unroll
    for (int g = 1; g < 8; ++g) M = fmaxf(M, sm.red[g]);
    float tot = 0.f;
    #pragma unroll
    for (int g = 0; g < 8; ++g) tot += sm.red[8 + g] * __builtin_amdgcn_exp2f(LOG2E*(sm.red[g] - M));
    float wv = __builtin_amdgcn_exp2f(LOG2E*(v - M)) * __builtin_amdgcn_rcpf(tot);
    sm.wsm[tid] = (_Float16)wv;
    __syncthreads();  // B2

    // ---- P3: ctx = w @ E via MFMA, swizzled ET reads ----
    f32x4 Ca[2];
    Ca[0] = (f32x4){0.f,0.f,0.f,0.f}; Ca[1] = (f32x4){0.f,0.f,0.f,0.f};
    #pragma unroll
    for (int kb = 0; kb < 16; ++kb) {
      const half8 bet = *(const half8*)&sm.ET[hrow*512 + (((kb*4 + lq) ^ hswz) << 3)];
      const half8 aw  = (l15 == 0) ? *(const half8*)&sm.wsm[kb*32 + lq*8] : Az;
      Ca[kb & 1] = __builtin_amdgcn_mfma_f32_16x16x32_f16(aw, bet, Ca[kb & 1], 0, 0, 0);
    }
    if (lane < 16)
      cxhR[wid*16 + l15] = (_Float16)(Ca[0][0] + Ca[1][0]);
    __syncthreads();  // B3

    // ---- P4: GRU MFMA (B streamed at use) + in-register gates ----
    half8 Ag[8];
    #pragma unroll
    for (int kb = 0; kb < 8; ++kb)
      Ag[kb] = (l15 == 0) ? *(const half8*)&cxhR[kb*32 + lq*8] : Az;
    f32x4 Cr, Cz, Cnh4, Cni4;
    Cr = (f32x4){0.f,0.f,0.f,0.f}; Cz = (f32x4){0.f,0.f,0.f,0.f};
    Cnh4 = (f32x4){0.f,0.f,0.f,0.f}; Cni4 = (f32x4){0.f,0.f,0.f,0.f};
    #pragma unroll
    for (int kb = 0; kb < 8; ++kb) {
      Cr = __builtin_amdgcn_mfma_f32_16x16x32_f16(Ag[kb], dFp[(Wb*48 +      sb*8 + kb)*64 + lane], Cr, 0, 0, 0);
      Cz = __builtin_amdgcn_mfma_f32_16x16x32_f16(Ag[kb], dFp[(Wb*48 + 16 + sb*8 + kb)*64 + lane], Cz, 0, 0, 0);
    }
    #pragma unroll
    for (int kb = 0; kb < 4; ++kb) {
      Cnh4 = __builtin_amdgcn_mfma_f32_16x16x32_f16(Ag[4 + kb], dFp[(Wb*48 + 32 + sb*4 + kb)*64 + lane], Cnh4, 0, 0, 0);
      Cni4 = __builtin_amdgcn_mfma_f32_16x16x32_f16(Ag[kb],     dFp[(Wb*48 + 40 + sb*4 + kb)*64 + lane], Cni4, 0, 0, 0);
    }
    if (lane < 16) {
      float xr = Cr[0] + bR, xz = Cz[0] + bZ;
      float r = __builtin_amdgcn_rcpf(1.f + __builtin_amdgcn_exp2f(-LOG2E*xr));
      float z = __builtin_amdgcn_rcpf(1.f + __builtin_amdgcn_exp2f(-LOG2E*xz));
      float narg = (Cni4[0] + bNI) + r * (Cnh4[0] + bNH);
      float n = 1.f - 2.f*__builtin_amdgcn_rcpf(__builtin_amdgcn_exp2f((2.f*LOG2E)*narg) + 1.f);
      float hnew = n + z*(sm.hsm[jg] - n);
      sm.hsm[jg] = hnew;
      _Float16 hf = (_Float16)hnew;
      sm.hh[jg] = hf;                      // next P1 A (after B4)
      cxhW[128 + jg] = hf;                 // next P4 A
      sm.hist[tt*128 + jg] = hf;           // epilogue
    }
    __syncthreads();  // B4
  }

  // ---- epilogue: out1+out2 for all 24 steps, wave 0, batched M=16 MFMA ----
  if (wid == 0) {
    #pragma unroll
    for (int chunk = 0; chunk < 2; ++chunk) {
      half8 Ae[4];
      #pragma unroll
      for (int kb = 0; kb < 4; ++kb) {
        int step = chunk*16 + l15;
        Ae[kb] = (step < TO) ? *(const half8*)&sm.hist[step*128 + kb*32 + lq*8] : Az;
      }
      f32x4 C0, C1;
      C0 = (f32x4){0.f,0.f,0.f,0.f}; C1 = (f32x4){0.f,0.f,0.f,0.f};
      #pragma unroll
      for (int kb = 0; kb < 4; ++kb) {
        C0 = __builtin_amdgcn_mfma_f32_16x16x32_f16(Ae[kb], oFp[kb*64 + lane],       C0, 0, 0, 0);
        C1 = __builtin_amdgcn_mfma_f32_16x16x32_f16(Ae[kb], oFp[(4 + kb)*64 + lane], C1, 0, 0, 0);
      }
      #pragma unroll
      for (int i = 0; i < 4; ++i) {
        int row = lq*4 + i, step = chunk*16 + row;
        float y0 = C0[i] + o1b0, y1 = C1[i] + o1b1;
        float part = fmaxf(y0, 0.f)*o2w0 + fmaxf(y1, 0.f)*o2w1;
        #pragma unroll
        for (int off = 1; off < 16; off <<= 1) part += __shfl_xor(part, off, 16);
        if (l15 == 0 && step < TO)
          out[(size_t)b*TO + step] = fmaxf(part + o2b, 0.f);
      }
    }
  }
}

extern "C" void kernel_launch(void* const* d_in, const int* in_sizes, int n_in,
                              void* d_out, int out_size, void* d_ws, size_t ws_size,
                              hipStream_t stream) {
  const float* xb      = (const float*)d_in[0];
  const float* enc_Wih = (const float*)d_in[1];
  const float* enc_Whh = (const float*)d_in[2];
  const float* enc_bih = (const float*)d_in[3];
  const float* enc_bhh = (const float*)d_in[4];
  const float* attn_W  = (const float*)d_in[5];
  const float* attn_b  = (const float*)d_in[6];
  const float* dec_Wih = (const float*)d_in[7];
  const float* dec_Whh = (const float*)d_in[8];
  const float* dec_bih = (const float*)d_in[9];
  const float* dec_bhh = (const float*)d_in[10];
  const float* out1_W  = (const float*)d_in[11];
  const float* out1_b  = (const float*)d_in[12];
  const float* out2_W  = (const float*)d_in[13];
  const float* out2_b  = (const float*)d_in[14];

  char* ws = (char*)d_ws;
  __half* enc_out = (__half*)(ws + OFF_ENCOUT);
  float*  hfin    = (float*)(ws + OFF_HFIN);
  __half* attnF   = (__half*)(ws + OFF_ATTNF);
  float*  attnB   = (float*)(ws + OFF_ATTNB);
  __half* decF    = (__half*)(ws + OFF_DECF);
  __half* out1F   = (__half*)(ws + OFF_OUT1F);
  __half* Wf      = (__half*)(ws + OFF_WF);

  prep_kernel<<<900, 256, 0, stream>>>(attn_W, attn_b, dec_Wih, dec_Whh, out1_W, out1_b,
                                       enc_Wih, enc_Whh, attnF, attnB, decF, out1F, Wf);
  enc_kernel<<<256, 256, 0, stream>>>(xb, Wf, enc_bih, enc_bhh, enc_out, hfin);
  dec_kernel<<<2048, 512, 0, stream>>>(xb, enc_out, hfin, attnF, attnB, attn_W, decF, out1F,
                                       dec_bih, dec_bhh, out1_W, out1_b, out2_W, out2_b,
                                       (float*)d_out);
}

// Round 14
// 1042.351 us; speedup vs baseline: 1.1187x; 1.0620x over previous
//
#include <hip/hip_runtime.h>
#include <hip/hip_fp16.h>

#define BB 2048
#define SS 512
#define FF 32
#define HH 128
#define TO 24
#define LOG2E 1.4426950408889634f

typedef unsigned int uint;
using half4 = __attribute__((ext_vector_type(4))) _Float16;
using half8 = __attribute__((ext_vector_type(8))) _Float16;
using f32x4 = __attribute__((ext_vector_type(4))) float;

// ---- workspace layout (bytes) ----
#define OFF_ENCOUT 0ull                                      // half[B][S][H]
#define OFF_HFIN  (OFF_ENCOUT + (size_t)BB*SS*HH*2)          // float[B][H]
#define OFF_ATTNF (OFF_HFIN + (size_t)BB*HH*4)               // half[65536]  fused logits B-frags (K=128)
#define OFF_ATTNB (OFF_ATTNF + (size_t)65536*2)              // float[512]   fused logit bias
#define OFF_DECF  (OFF_ATTNB + (size_t)512*4)                // half[98304]  GRU B-frags
#define OFF_OUT1F (OFF_DECF + (size_t)98304*2)               // half[4096]   out1 B-frags
#define OFF_WF    (OFF_OUT1F + (size_t)4096*2)               // half[61440]  enc B-frags

// ================= prep: fuse attn+out1, pack all weights into MFMA frag order =================
__global__ void prep_kernel(const float* attn_W, const float* attn_b,
                            const float* dec_Wih, const float* dec_Whh,
                            const float* out1_W, const float* out1_b,
                            const float* enc_Wih, const float* enc_Whh,
                            __half* attnF, float* attnB, __half* decF, __half* out1F, __half* Wf) {
  int i = blockIdx.x * 256 + threadIdx.x;
  if (i < 65536) {
    // fused A~[s][h] frags: idx = ((w*4+st)*4+kb)*512 + l*8 + e
    int e = i & 7, l = (i >> 3) & 63, kb = (i >> 9) & 3, st = (i >> 11) & 3, w = i >> 13;
    int h = kb*32 + ((l >> 4) << 3) + e;
    int s = w*64 + st*16 + (l & 15);
    float acc = attn_W[s*160 + h];
    #pragma unroll 8
    for (int f = 0; f < 32; ++f) acc += out1_W[f*128 + h] * attn_W[s*160 + 128 + f];
    attnF[i] = __float2half(acc);
    return;
  }
  i -= 65536;
  if (i < 512) {               // b~[s] = attn_b[s] + sum_f out1_b[f]*A_y[s][f]
    float acc = attn_b[i];
    #pragma unroll 8
    for (int f = 0; f < 32; ++f) acc += out1_b[f] * attn_W[i*160 + 128 + f];
    attnB[i] = acc;
    return;
  }
  i -= 512;
  if (i < 98304) {
    int e = i & 7, l = (i >> 3) & 63, fi = (i >> 9) % 48, w = i / 24576;
    int lq = l >> 4, l15 = l & 15;
    float val;
    if (fi < 32) {            // r/z combined [ctx|h] K=256
      int g2 = fi >> 4, sub = (fi >> 3) & 1, kb = fi & 7;
      int k = kb*32 + lq*8 + e, j = w*32 + sub*16 + l15, jg = g2*128 + j;
      val = (k < 128) ? dec_Wih[jg*128 + k] : dec_Whh[jg*128 + (k - 128)];
    } else {                  // nh (Whh) then ni (Wih), K=128 each
      int f2 = fi - 32, cat = f2 >> 3, sub = (f2 >> 2) & 1, kb4 = f2 & 3;
      int k = kb4*32 + lq*8 + e, j = 256 + w*32 + sub*16 + l15;
      val = cat ? dec_Wih[j*128 + k] : dec_Whh[j*128 + k];
    }
    decF[i] = __float2half(val);
    return;
  }
  i -= 98304;
  if (i < 4096) {             // out1F frags: tile(2) x kb(4) x lane x e
    int e = i & 7, l = (i >> 3) & 63, kb = (i >> 9) & 3, tile = (i >> 11) & 1;
    int k = kb*32 + ((l >> 4) << 3) + e;
    int f = tile*16 + (l & 15);
    out1F[i] = __float2half(out1_W[f*128 + k]);
    return;
  }
  i -= 4096;
  if (i < 61440) {
    int e = i & 7, l = (i >> 3) & 63, q = i >> 9;
    int kb = q % 5, tt = (q / 5) % 6, w = q / 30;
    int g = tt >> 1, sub = tt & 1;
    int k = kb*32 + ((l >> 4) << 3) + e;
    int J = g*128 + w*32 + sub*16 + (l & 15);
    float v = (k < 128) ? enc_Whh[J*128 + k] : enc_Wih[J*32 + (k - 128)];
    Wf[i] = __float2half(v);
  }
}

// ================= encoder: MFMA, 8 batches/block, ping-pong hx, 1 barrier/step =================
#define HXS 168

__global__ void __launch_bounds__(256, 1) enc_kernel(
    const float* __restrict__ xb, const __half* __restrict__ Wf,
    const float* __restrict__ bih, const float* __restrict__ bhh,
    __half* __restrict__ enc_out, float* __restrict__ hfin) {
  __shared__ __align__(16) _Float16 hx[2][16][HXS];   // rows 0..7 live, 8..15 zero
  const int tid  = threadIdx.x;
  const int lane = tid & 63, wid = tid >> 6;
  const int l15  = lane & 15, lq = lane >> 4;
  const int b0   = blockIdx.x * 8;

  half8 Bf[6][5];
  { const half8* wfp = (const half8*)Wf;
    #pragma unroll
    for (int tt = 0; tt < 6; ++tt)
      #pragma unroll
      for (int kb = 0; kb < 5; ++kb)
        Bf[tt][kb] = wfp[((wid*6 + tt)*5 + kb)*64 + lane];
  }

  float br[2], bz[2], bnh[2], bni[2];
  #pragma unroll
  for (int sub = 0; sub < 2; ++sub) {
    int j = wid*32 + sub*16 + l15;
    br[sub]  = bih[j]       + bhh[j];
    bz[sub]  = bih[128 + j] + bhh[128 + j];
    bnh[sub] = bhh[256 + j];
    bni[sub] = bih[256 + j];
  }
  float hreg[2][4] = {{0.f,0.f,0.f,0.f},{0.f,0.f,0.f,0.f}};

  const int m2 = tid >> 5, c2 = tid & 31;   // staging: 8 rows x 32 cols
  const float* xbase = xb + ((size_t)(b0 + m2)*512)*32 + c2;

  for (int i = tid; i < 2*16*HXS; i += 256) (&hx[0][0][0])[i] = (_Float16)0.f;
  __syncthreads();
  hx[0][m2][128 + c2] = (_Float16)xbase[0];
  __syncthreads();

  float xq_next = xbase[1*32];    // x_{t+1} pipeline register

  int p = 0;
  for (int t = 0; t < 512; ++t) {
    const int tn2 = (t < 510) ? t + 2 : 511;
    float xq_new = xbase[(size_t)tn2*32];

    half8 A[5];
    #pragma unroll
    for (int kb = 0; kb < 5; ++kb)
      A[kb] = *(const half8*)&hx[p][l15][kb*32 + lq*8];

    f32x4 Cr[2], Cz[2], Cnh[2], Cni[2];
    #pragma unroll
    for (int sub = 0; sub < 2; ++sub) {
      Cr[sub] = (f32x4){0.f,0.f,0.f,0.f};
      Cz[sub] = (f32x4){0.f,0.f,0.f,0.f};
      Cnh[sub] = (f32x4){0.f,0.f,0.f,0.f};
      Cni[sub] = (f32x4){0.f,0.f,0.f,0.f};
    }
    #pragma unroll
    for (int sub = 0; sub < 2; ++sub) {
      #pragma unroll
      for (int kb = 0; kb < 5; ++kb) {
        Cr[sub] = __builtin_amdgcn_mfma_f32_16x16x32_f16(A[kb], Bf[sub][kb],     Cr[sub], 0, 0, 0);
        Cz[sub] = __builtin_amdgcn_mfma_f32_16x16x32_f16(A[kb], Bf[2 + sub][kb], Cz[sub], 0, 0, 0);
      }
      #pragma unroll
      for (int kb = 0; kb < 4; ++kb)
        Cnh[sub] = __builtin_amdgcn_mfma_f32_16x16x32_f16(A[kb], Bf[4 + sub][kb], Cnh[sub], 0, 0, 0);
      Cni[sub] = __builtin_amdgcn_mfma_f32_16x16x32_f16(A[4], Bf[4 + sub][4], Cni[sub], 0, 0, 0);
    }

    // gates: write h_t and x_{t+1} into the OTHER buffer
    #pragma unroll
    for (int sub = 0; sub < 2; ++sub)
      #pragma unroll
      for (int i = 0; i < 4; ++i) {
        float xr = Cr[sub][i] + br[sub];
        float xz = Cz[sub][i] + bz[sub];
        float r = __builtin_amdgcn_rcpf(1.f + __builtin_amdgcn_exp2f(-LOG2E*xr));
        float z = __builtin_amdgcn_rcpf(1.f + __builtin_amdgcn_exp2f(-LOG2E*xz));
        float narg = (Cni[sub][i] + bni[sub]) + r * (Cnh[sub][i] + bnh[sub]);
        float n = 1.f - 2.f*__builtin_amdgcn_rcpf(__builtin_amdgcn_exp2f((2.f*LOG2E)*narg) + 1.f);
        float hnew = n + z*(hreg[sub][i] - n);
        hreg[sub][i] = hnew;
        if (lq < 2)
          hx[p ^ 1][4*lq + i][wid*32 + sub*16 + l15] = (_Float16)hnew;
      }
    hx[p ^ 1][m2][128 + c2] = (_Float16)xq_next;
    xq_next = xq_new;
    __syncthreads();   // single barrier per step

    { half4 hv = *(const half4*)&hx[p ^ 1][m2][c2*4];
      *(half4*)((void*)&enc_out[((size_t)(b0 + m2)*512 + t)*128 + c2*4]) = hv; }
    p ^= 1;
  }

  if (lq < 2)
    #pragma unroll
    for (int sub = 0; sub < 2; ++sub)
      #pragma unroll
      for (int i = 0; i < 4; ++i)
        hfin[(size_t)(b0 + 4*lq + i)*128 + wid*32 + sub*16 + l15] = hreg[sub][i];
}

// ================= decoder: 4 barriers/step, fused-attn, GRU prefetch (256-VGPR budget),
//                   no-max softmax, batched out epilogue =================
struct DecSmem {
  _Float16 ET[128*512];   // 128 KB, swizzled: (h,s) -> h*512 + ((s>>3 ^ (h&7) ^ ((h>>3)&7))<<3) + (s&7)
  _Float16 wsm[512];      // softmax weights fp16
  float hsm[128];         // h fp32 (gate carry)
  _Float16 hh[128];       // h fp16 (P1 A operand)
  _Float16 cxh[2][256];   // ping-pong [ctx | h]
  _Float16 hist[TO*128];  // h history for out epilogue
  float red[16];
  float d32[32];          // y0 - out1(h0)
};

__global__ void __launch_bounds__(512, 1) dec_kernel(const float* __restrict__ xb,
    const __half* __restrict__ enc_out, const float* __restrict__ hfin,
    const __half* __restrict__ attnF, const float* __restrict__ attnB,
    const float* __restrict__ attn_W,
    const __half* __restrict__ decF, const __half* __restrict__ out1F,
    const float* __restrict__ dbih, const float* __restrict__ dbhh,
    const float* __restrict__ out1_W, const float* __restrict__ out1_b,
    const float* __restrict__ out2_W, const float* __restrict__ out2_b,
    float* __restrict__ out) {
  __shared__ __align__(16) DecSmem sm;
  const int tid = threadIdx.x, lane = tid & 63, wid = tid >> 6;
  const int l15 = lane & 15, lq = lane >> 4;
  const int b = blockIdx.x;

  const half8* aFp = (const half8*)attnF;
  const half8* dFp = (const half8*)decF;
  const half8* oFp = (const half8*)out1F;
  const int Wb = wid >> 1, sb = wid & 1;

  // ---- per-thread scalar params ----
  const float ab = attnB[tid];                       // fused logit bias for s = tid
  const int jg = wid*16 + l15;                       // this wave's gate col
  const float bR  = dbih[jg]       + dbhh[jg];
  const float bZ  = dbih[128 + jg] + dbhh[128 + jg];
  const float bNH = dbhh[256 + jg];
  const float bNI = dbih[256 + jg];
  const float o1b0 = out1_b[l15], o1b1 = out1_b[16 + l15];
  const float o2w0 = out2_W[l15], o2w1 = out2_W[16 + l15];
  const float o2b  = out2_b[0];

  // ---- staging: E transposed+swizzled into LDS; h0; step-0 logit correction ----
  { const half8* src = (const half8*)(enc_out + (size_t)b*512*128);
    for (int i = tid; i < 8192; i += 512) {
      half8 v = src[i];
      int s = i >> 4, h0 = (i & 15) * 8, sg = s >> 3, s7 = s & 7;
      #pragma unroll
      for (int j = 0; j < 8; ++j) {
        int h = h0 + j;
        sm.ET[h*512 + (((sg ^ (h & 7) ^ ((h >> 3) & 7)) << 3)) + s7] = v[j];
      }
    } }
  if (tid < 128) { float hv = hfin[(size_t)b*128 + tid];
    sm.hsm[tid] = hv; sm.hh[tid] = (_Float16)hv; sm.cxh[0][128 + tid] = (_Float16)hv; }
  if (tid < 32) {
    // d32 = y0 - out1(h0)   (exact fp32)
    float o1v = out1_b[tid];
    for (int h = 0; h < 128; ++h) o1v += out1_W[tid*128 + h] * hfin[(size_t)b*128 + h];
    sm.d32[tid] = xb[((size_t)b*512 + 511)*32 + tid] - o1v;
  }
  __syncthreads();
  float c0reg = 0.f;     // per-thread (s = tid) step-0 correction
  #pragma unroll 8
  for (int f = 0; f < 32; ++f) c0reg += sm.d32[f] * attn_W[tid*160 + 128 + f];

  const half8 Az = {};
  const int hrow = wid*16 + l15;                     // P3 B-operand row
  const int hswz = (hrow & 7) ^ ((hrow >> 3) & 7);   // its swizzle key

  for (int tt = 0; tt < TO; ++tt) {
    _Float16* cxhR = sm.cxh[tt & 1];         // read buffer (ctx_t | h_{t-1})
    _Float16* cxhW = sm.cxh[(tt & 1) ^ 1];   // write buffer (h_t)

    // ---- prefetch GRU B-frags (96 VGPRs, live through P1-P3; 256-VGPR budget) ----
    half8 pRzR[8], pRzZ[8], pNh[4], pNi[4];
    #pragma unroll
    for (int kb = 0; kb < 8; ++kb) {
      pRzR[kb] = dFp[(Wb*48 +      sb*8 + kb)*64 + lane];
      pRzZ[kb] = dFp[(Wb*48 + 16 + sb*8 + kb)*64 + lane];
    }
    #pragma unroll
    for (int kb = 0; kb < 4; ++kb) {
      pNh[kb] = dFp[(Wb*48 + 32 + sb*4 + kb)*64 + lane];
      pNi[kb] = dFp[(Wb*48 + 40 + sb*4 + kb)*64 + lane];
    }

    // ---- P1: fused logits MFMA (K=128) + no-max wave softmax partial ----
    half8 A[4];
    #pragma unroll
    for (int kb = 0; kb < 4; ++kb)
      A[kb] = (l15 == 0) ? *(const half8*)&sm.hh[kb*32 + lq*8] : Az;
    f32x4 CL[4];
    #pragma unroll
    for (int stt = 0; stt < 4; ++stt) CL[stt] = (f32x4){0.f,0.f,0.f,0.f};
    #pragma unroll
    for (int stt = 0; stt < 4; ++stt)
      #pragma unroll
      for (int kb = 0; kb < 4; ++kb)
        CL[stt] = __builtin_amdgcn_mfma_f32_16x16x32_f16(
            A[kb], aFp[((wid*4 + stt)*4 + kb)*64 + lane], CL[stt], 0, 0, 0);
    // redistribute: thread tid gets logit s = tid  (s = wid*64 + lq*16 + l15)
    float t0 = __shfl(CL[0][0], l15), t1 = __shfl(CL[1][0], l15);
    float t2 = __shfl(CL[2][0], l15), t3 = __shfl(CL[3][0], l15);
    float v = (lq == 0) ? t0 : (lq == 1) ? t1 : (lq == 2) ? t2 : t3;
    v += ab;
    if (tt == 0) v += c0reg;
    // |h|<1 and |A~ rows| bounded => |v| <~ 8: exp without max-subtraction is safe in fp32
    float ex = __builtin_amdgcn_exp2f(LOG2E*v);
    float sw = ex;
    #pragma unroll
    for (int off = 1; off < 64; off <<= 1) sw += __shfl_xor(sw, off);
    if (lane == 0) sm.red[wid] = sw;
    __syncthreads();  // B1

    // ---- P2: softmax finalize, write w fp16 ----
    float tot = sm.red[0];
    #pragma unroll
    for (int g = 1; g < 8; ++g) tot += sm.red[g];
    sm.wsm[tid] = (_Float16)(ex * __builtin_amdgcn_rcpf(tot));
    __syncthreads();  // B2

    // ---- P3: ctx = w @ E via MFMA, swizzled ET reads ----
    f32x4 Ca[2];
    Ca[0] = (f32x4){0.f,0.f,0.f,0.f}; Ca[1] = (f32x4){0.f,0.f,0.f,0.f};
    #pragma unroll
    for (int kb = 0; kb < 16; ++kb) {
      const half8 bet = *(const half8*)&sm.ET[hrow*512 + (((kb*4 + lq) ^ hswz) << 3)];
      const half8 aw  = (l15 == 0) ? *(const half8*)&sm.wsm[kb*32 + lq*8] : Az;
      Ca[kb & 1] = __builtin_amdgcn_mfma_f32_16x16x32_f16(aw, bet, Ca[kb & 1], 0, 0, 0);
    }
    if (lane < 16)
      cxhR[wid*16 + l15] = (_Float16)(Ca[0][0] + Ca[1][0]);
    __syncthreads();  // B3

    // ---- P4: GRU MFMA (prefetched B) + in-register gates ----
    half8 Ag[8];
    #pragma unroll
    for (int kb = 0; kb < 8; ++kb)
      Ag[kb] = (l15 == 0) ? *(const half8*)&cxhR[kb*32 + lq*8] : Az;
    f32x4 Cr, Cz, Cnh4, Cni4;
    Cr = (f32x4){0.f,0.f,0.f,0.f}; Cz = (f32x4){0.f,0.f,0.f,0.f};
    Cnh4 = (f32x4){0.f,0.f,0.f,0.f}; Cni4 = (f32x4){0.f,0.f,0.f,0.f};
    #pragma unroll
    for (int kb = 0; kb < 8; ++kb) {
      Cr = __builtin_amdgcn_mfma_f32_16x16x32_f16(Ag[kb], pRzR[kb], Cr, 0, 0, 0);
      Cz = __builtin_amdgcn_mfma_f32_16x16x32_f16(Ag[kb], pRzZ[kb], Cz, 0, 0, 0);
    }
    #pragma unroll
    for (int kb = 0; kb < 4; ++kb) {
      Cnh4 = __builtin_amdgcn_mfma_f32_16x16x32_f16(Ag[4 + kb], pNh[kb], Cnh4, 0, 0, 0);
      Cni4 = __builtin_amdgcn_mfma_f32_16x16x32_f16(Ag[kb],     pNi[kb], Cni4, 0, 0, 0);
    }
    if (lane < 16) {
      float xr = Cr[0] + bR, xz = Cz[0] + bZ;
      float r = __builtin_amdgcn_rcpf(1.f + __builtin_amdgcn_exp2f(-LOG2E*xr));
      float z = __builtin_amdgcn_rcpf(1.f + __builtin_amdgcn_exp2f(-LOG2E*xz));
      float narg = (Cni4[0] + bNI) + r * (Cnh4[0] + bNH);
      float n = 1.f - 2.f*__builtin_amdgcn_rcpf(__builtin_amdgcn_exp2f((2.f*LOG2E)*narg) + 1.f);
      float hnew = n + z*(sm.hsm[jg] - n);
      sm.hsm[jg] = hnew;
      _Float16 hf = (_Float16)hnew;
      sm.hh[jg] = hf;                      // next P1 A (after B4)
      cxhW[128 + jg] = hf;                 // next P4 A
      sm.hist[tt*128 + jg] = hf;           // epilogue
    }
    __syncthreads();  // B4
  }

  // ---- epilogue: out1+out2 for all 24 steps, wave 0, batched M=16 MFMA ----
  if (wid == 0) {
    #pragma unroll
    for (int chunk = 0; chunk < 2; ++chunk) {
      half8 Ae[4];
      #pragma unroll
      for (int kb = 0; kb < 4; ++kb) {
        int step = chunk*16 + l15;
        Ae[kb] = (step < TO) ? *(const half8*)&sm.hist[step*128 + kb*32 + lq*8] : Az;
      }
      f32x4 C0, C1;
      C0 = (f32x4){0.f,0.f,0.f,0.f}; C1 = (f32x4){0.f,0.f,0.f,0.f};
      #pragma unroll
      for (int kb = 0; kb < 4; ++kb) {
        C0 = __builtin_amdgcn_mfma_f32_16x16x32_f16(Ae[kb], oFp[kb*64 + lane],       C0, 0, 0, 0);
        C1 = __builtin_amdgcn_mfma_f32_16x16x32_f16(Ae[kb], oFp[(4 + kb)*64 + lane], C1, 0, 0, 0);
      }
      #pragma unroll
      for (int i = 0; i < 4; ++i) {
        int row = lq*4 + i, step = chunk*16 + row;
        float y0 = C0[i] + o1b0, y1 = C1[i] + o1b1;
        float part = fmaxf(y0, 0.f)*o2w0 + fmaxf(y1, 0.f)*o2w1;
        #pragma unroll
        for (int off = 1; off < 16; off <<= 1) part += __shfl_xor(part, off, 16);
        if (l15 == 0 && step < TO)
          out[(size_t)b*TO + step] = fmaxf(part + o2b, 0.f);
      }
    }
  }
}

extern "C" void kernel_launch(void* const* d_in, const int* in_sizes, int n_in,
                              void* d_out, int out_size, void* d_ws, size_t ws_size,
                              hipStream_t stream) {
  const float* xb      = (const float*)d_in[0];
  const float* enc_Wih = (const float*)d_in[1];
  const float* enc_Whh = (const float*)d_in[2];
  const float* enc_bih = (const float*)d_in[3];
  const float* enc_bhh = (const float*)d_in[4];
  const float* attn_W  = (const float*)d_in[5];
  const float* attn_b  = (const float*)d_in[6];
  const float* dec_Wih = (const float*)d_in[7];
  const float* dec_Whh = (const float*)d_in[8];
  const float* dec_bih = (const float*)d_in[9];
  const float* dec_bhh = (const float*)d_in[10];
  const float* out1_W  = (const float*)d_in[11];
  const float* out1_b  = (const float*)d_in[12];
  const float* out2_W  = (const float*)d_in[13];
  const float* out2_b  = (const float*)d_in[14];

  char* ws = (char*)d_ws;
  __half* enc_out = (__half*)(ws + OFF_ENCOUT);
  float*  hfin    = (float*)(ws + OFF_HFIN);
  __half* attnF   = (__half*)(ws + OFF_ATTNF);
  float*  attnB   = (float*)(ws + OFF_ATTNB);
  __half* decF    = (__half*)(ws + OFF_DECF);
  __half* out1F   = (__half*)(ws + OFF_OUT1F);
  __half* Wf      = (__half*)(ws + OFF_WF);

  prep_kernel<<<900, 256, 0, stream>>>(attn_W, attn_b, dec_Wih, dec_Whh, out1_W, out1_b,
                                       enc_Wih, enc_Whh, attnF, attnB, decF, out1F, Wf);
  enc_kernel<<<256, 256, 0, stream>>>(xb, Wf, enc_bih, enc_bhh, enc_out, hfin);
  dec_kernel<<<2048, 512, 0, stream>>>(xb, enc_out, hfin, attnF, attnB, attn_W, decF, out1F,
                                       dec_bih, dec_bhh, out1_W, out1_b, out2_W, out2_b,
                                       (float*)d_out);
}

// Round 15
// 1028.878 us; speedup vs baseline: 1.1333x; 1.0131x over previous
//
#include <hip/hip_runtime.h>
#include <hip/hip_fp16.h>

#define BB 2048
#define SS 512
#define FF 32
#define HH 128
#define TO 24
#define LOG2E 1.4426950408889634f

typedef unsigned int uint;
using half4 = __attribute__((ext_vector_type(4))) _Float16;
using half8 = __attribute__((ext_vector_type(8))) _Float16;
using f32x4 = __attribute__((ext_vector_type(4))) float;

// ---- workspace layout (bytes) ----
#define OFF_ENCOUT 0ull                                      // half[B][S][H]
#define OFF_HFIN  (OFF_ENCOUT + (size_t)BB*SS*HH*2)          // float[B][H]
#define OFF_ATTNF (OFF_HFIN + (size_t)BB*HH*4)               // half[65536]  fused logits B-frags (K=128)
#define OFF_ATTNB (OFF_ATTNF + (size_t)65536*2)              // float[512]   fused logit bias
#define OFF_DECF  (OFF_ATTNB + (size_t)512*4)                // half[98304]  GRU B-frags
#define OFF_OUT1F (OFF_DECF + (size_t)98304*2)               // half[4096]   out1 B-frags
#define OFF_WF    (OFF_OUT1F + (size_t)4096*2)               // half[61440]  enc B-frags

// ================= prep: fuse attn+out1, pack all weights into MFMA frag order =================
__global__ void prep_kernel(const float* attn_W, const float* attn_b,
                            const float* dec_Wih, const float* dec_Whh,
                            const float* out1_W, const float* out1_b,
                            const float* enc_Wih, const float* enc_Whh,
                            __half* attnF, float* attnB, __half* decF, __half* out1F, __half* Wf) {
  int i = blockIdx.x * 256 + threadIdx.x;
  if (i < 65536) {
    // fused A~[s][h] frags: idx = ((w*4+st)*4+kb)*512 + l*8 + e
    int e = i & 7, l = (i >> 3) & 63, kb = (i >> 9) & 3, st = (i >> 11) & 3, w = i >> 13;
    int h = kb*32 + ((l >> 4) << 3) + e;
    int s = w*64 + st*16 + (l & 15);
    float acc = attn_W[s*160 + h];
    #pragma unroll 8
    for (int f = 0; f < 32; ++f) acc += out1_W[f*128 + h] * attn_W[s*160 + 128 + f];
    attnF[i] = __float2half(acc);
    return;
  }
  i -= 65536;
  if (i < 512) {               // b~[s] = attn_b[s] + sum_f out1_b[f]*A_y[s][f]
    float acc = attn_b[i];
    #pragma unroll 8
    for (int f = 0; f < 32; ++f) acc += out1_b[f] * attn_W[i*160 + 128 + f];
    attnB[i] = acc;
    return;
  }
  i -= 512;
  if (i < 98304) {
    int e = i & 7, l = (i >> 3) & 63, fi = (i >> 9) % 48, w = i / 24576;
    int lq = l >> 4, l15 = l & 15;
    float val;
    if (fi < 32) {            // r/z combined [ctx|h] K=256
      int g2 = fi >> 4, sub = (fi >> 3) & 1, kb = fi & 7;
      int k = kb*32 + lq*8 + e, j = w*32 + sub*16 + l15, jg = g2*128 + j;
      val = (k < 128) ? dec_Wih[jg*128 + k] : dec_Whh[jg*128 + (k - 128)];
    } else {                  // nh (Whh) then ni (Wih), K=128 each
      int f2 = fi - 32, cat = f2 >> 3, sub = (f2 >> 2) & 1, kb4 = f2 & 3;
      int k = kb4*32 + lq*8 + e, j = 256 + w*32 + sub*16 + l15;
      val = cat ? dec_Wih[j*128 + k] : dec_Whh[j*128 + k];
    }
    decF[i] = __float2half(val);
    return;
  }
  i -= 98304;
  if (i < 4096) {             // out1F frags: tile(2) x kb(4) x lane x e
    int e = i & 7, l = (i >> 3) & 63, kb = (i >> 9) & 3, tile = (i >> 11) & 1;
    int k = kb*32 + ((l >> 4) << 3) + e;
    int f = tile*16 + (l & 15);
    out1F[i] = __float2half(out1_W[f*128 + k]);
    return;
  }
  i -= 4096;
  if (i < 61440) {
    int e = i & 7, l = (i >> 3) & 63, q = i >> 9;
    int kb = q % 5, tt = (q / 5) % 6, w = q / 30;
    int g = tt >> 1, sub = tt & 1;
    int k = kb*32 + ((l >> 4) << 3) + e;
    int J = g*128 + w*32 + sub*16 + (l & 15);
    float v = (k < 128) ? enc_Whh[J*128 + k] : enc_Wih[J*32 + (k - 128)];
    Wf[i] = __float2half(v);
  }
}

// ================= encoder: MFMA, 8 batches/block, ping-pong hx, 1 barrier/step =================
#define HXS 168

__global__ void __launch_bounds__(256, 1) enc_kernel(
    const float* __restrict__ xb, const __half* __restrict__ Wf,
    const float* __restrict__ bih, const float* __restrict__ bhh,
    __half* __restrict__ enc_out, float* __restrict__ hfin) {
  __shared__ __align__(16) _Float16 hx[2][16][HXS];   // rows 0..7 live, 8..15 zero
  const int tid  = threadIdx.x;
  const int lane = tid & 63, wid = tid >> 6;
  const int l15  = lane & 15, lq = lane >> 4;
  const int b0   = blockIdx.x * 8;

  half8 Bf[6][5];
  { const half8* wfp = (const half8*)Wf;
    #pragma unroll
    for (int tt = 0; tt < 6; ++tt)
      #pragma unroll
      for (int kb = 0; kb < 5; ++kb)
        Bf[tt][kb] = wfp[((wid*6 + tt)*5 + kb)*64 + lane];
  }

  float br[2], bz[2], bnh[2], bni[2];
  #pragma unroll
  for (int sub = 0; sub < 2; ++sub) {
    int j = wid*32 + sub*16 + l15;
    br[sub]  = bih[j]       + bhh[j];
    bz[sub]  = bih[128 + j] + bhh[128 + j];
    bnh[sub] = bhh[256 + j];
    bni[sub] = bih[256 + j];
  }
  float hreg[2][4] = {{0.f,0.f,0.f,0.f},{0.f,0.f,0.f,0.f}};

  const int m2 = tid >> 5, c2 = tid & 31;   // staging: 8 rows x 32 cols
  const float* xbase = xb + ((size_t)(b0 + m2)*512)*32 + c2;

  for (int i = tid; i < 2*16*HXS; i += 256) (&hx[0][0][0])[i] = (_Float16)0.f;
  __syncthreads();
  hx[0][m2][128 + c2] = (_Float16)xbase[0];
  __syncthreads();

  float xq_next = xbase[1*32];    // x_{t+1} pipeline register

  int p = 0;
  for (int t = 0; t < 512; ++t) {
    const int tn2 = (t < 510) ? t + 2 : 511;
    float xq_new = xbase[(size_t)tn2*32];

    half8 A[5];
    #pragma unroll
    for (int kb = 0; kb < 5; ++kb)
      A[kb] = *(const half8*)&hx[p][l15][kb*32 + lq*8];

    f32x4 Cr[2], Cz[2], Cnh[2], Cni[2];
    #pragma unroll
    for (int sub = 0; sub < 2; ++sub) {
      Cr[sub] = (f32x4){0.f,0.f,0.f,0.f};
      Cz[sub] = (f32x4){0.f,0.f,0.f,0.f};
      Cnh[sub] = (f32x4){0.f,0.f,0.f,0.f};
      Cni[sub] = (f32x4){0.f,0.f,0.f,0.f};
    }
    #pragma unroll
    for (int sub = 0; sub < 2; ++sub) {
      #pragma unroll
      for (int kb = 0; kb < 5; ++kb) {
        Cr[sub] = __builtin_amdgcn_mfma_f32_16x16x32_f16(A[kb], Bf[sub][kb],     Cr[sub], 0, 0, 0);
        Cz[sub] = __builtin_amdgcn_mfma_f32_16x16x32_f16(A[kb], Bf[2 + sub][kb], Cz[sub], 0, 0, 0);
      }
      #pragma unroll
      for (int kb = 0; kb < 4; ++kb)
        Cnh[sub] = __builtin_amdgcn_mfma_f32_16x16x32_f16(A[kb], Bf[4 + sub][kb], Cnh[sub], 0, 0, 0);
      Cni[sub] = __builtin_amdgcn_mfma_f32_16x16x32_f16(A[4], Bf[4 + sub][4], Cni[sub], 0, 0, 0);
    }

    // gates: write h_t and x_{t+1} into the OTHER buffer
    #pragma unroll
    for (int sub = 0; sub < 2; ++sub)
      #pragma unroll
      for (int i = 0; i < 4; ++i) {
        float xr = Cr[sub][i] + br[sub];
        float xz = Cz[sub][i] + bz[sub];
        float r = __builtin_amdgcn_rcpf(1.f + __builtin_amdgcn_exp2f(-LOG2E*xr));
        float z = __builtin_amdgcn_rcpf(1.f + __builtin_amdgcn_exp2f(-LOG2E*xz));
        float narg = (Cni[sub][i] + bni[sub]) + r * (Cnh[sub][i] + bnh[sub]);
        float n = 1.f - 2.f*__builtin_amdgcn_rcpf(__builtin_amdgcn_exp2f((2.f*LOG2E)*narg) + 1.f);
        float hnew = n + z*(hreg[sub][i] - n);
        hreg[sub][i] = hnew;
        if (lq < 2)
          hx[p ^ 1][4*lq + i][wid*32 + sub*16 + l15] = (_Float16)hnew;
      }
    hx[p ^ 1][m2][128 + c2] = (_Float16)xq_next;
    xq_next = xq_new;
    __syncthreads();   // single barrier per step

    { half4 hv = *(const half4*)&hx[p ^ 1][m2][c2*4];
      *(half4*)((void*)&enc_out[((size_t)(b0 + m2)*512 + t)*128 + c2*4]) = hv; }
    p ^= 1;
  }

  if (lq < 2)
    #pragma unroll
    for (int sub = 0; sub < 2; ++sub)
      #pragma unroll
      for (int i = 0; i < 4; ++i)
        hfin[(size_t)(b0 + 4*lq + i)*128 + wid*32 + sub*16 + l15] = hreg[sub][i];
}

// ================= decoder: persistent GRU frags (96 VGPR), pipelined attnF,
//                   no-max softmax, 4 barriers/step, batched epilogue ============
struct DecSmem {
  _Float16 ET[128*512];   // 128 KB, swizzled: (h,s) -> h*512 + ((s>>3 ^ (h&7) ^ ((h>>3)&7))<<3) + (s&7)
  _Float16 wsm[512];      // softmax weights fp16
  float hsm[128];         // h fp32 (gate carry)
  _Float16 hh[128];       // h fp16 (P1 A operand)
  _Float16 cxh[2][256];   // ping-pong [ctx | h]
  _Float16 hist[TO*128];  // h history for out epilogue
  float red[16];
  float d32[32];          // y0 - out1(h0)
};

__global__ void __launch_bounds__(512)
__attribute__((amdgpu_waves_per_eu(2, 2)))
dec_kernel(const float* __restrict__ xb,
    const __half* __restrict__ enc_out, const float* __restrict__ hfin,
    const __half* __restrict__ attnF, const float* __restrict__ attnB,
    const float* __restrict__ attn_W,
    const __half* __restrict__ decF, const __half* __restrict__ out1F,
    const float* __restrict__ dbih, const float* __restrict__ dbhh,
    const float* __restrict__ out1_W, const float* __restrict__ out1_b,
    const float* __restrict__ out2_W, const float* __restrict__ out2_b,
    float* __restrict__ out) {
  __shared__ __align__(16) DecSmem sm;
  const int tid = threadIdx.x, lane = tid & 63, wid = tid >> 6;
  const int l15 = lane & 15, lq = lane >> 4;
  const int b = blockIdx.x;

  const half8* aFp = (const half8*)attnF;
  const half8* dFp = (const half8*)decF;
  const half8* oFp = (const half8*)out1F;
  const int Wb = wid >> 1, sb = wid & 1;

  // ---- per-thread scalar params ----
  const float ab = attnB[tid];                       // fused logit bias for s = tid
  const int jg = wid*16 + l15;                       // this wave's gate col
  const float bR  = dbih[jg]       + dbhh[jg];
  const float bZ  = dbih[128 + jg] + dbhh[128 + jg];
  const float bNH = dbhh[256 + jg];
  const float bNI = dbih[256 + jg];
  const float o1b0 = out1_b[l15], o1b1 = out1_b[16 + l15];
  const float o2w0 = out2_W[l15], o2w1 = out2_W[16 + l15];
  const float o2b  = out2_b[0];

  // ---- persistent GRU B-frags: 24 half8 = 96 VGPR, live across the whole tt-loop ----
  half8 pRzR[8], pRzZ[8], pNh[4], pNi[4];
  #pragma unroll
  for (int kb = 0; kb < 8; ++kb) {
    pRzR[kb] = dFp[(Wb*48 +      sb*8 + kb)*64 + lane];
    pRzZ[kb] = dFp[(Wb*48 + 16 + sb*8 + kb)*64 + lane];
  }
  #pragma unroll
  for (int kb = 0; kb < 4; ++kb) {
    pNh[kb] = dFp[(Wb*48 + 32 + sb*4 + kb)*64 + lane];
    pNi[kb] = dFp[(Wb*48 + 40 + sb*4 + kb)*64 + lane];
  }
  // ---- attnF pipeline buffer: step-0 frags (reloaded each step at P3-start) ----
  half8 aF[4][4];
  #pragma unroll
  for (int stt = 0; stt < 4; ++stt)
    #pragma unroll
    for (int kb = 0; kb < 4; ++kb)
      aF[stt][kb] = aFp[((wid*4 + stt)*4 + kb)*64 + lane];

  // ---- staging: E transposed+swizzled into LDS; h0; step-0 logit correction ----
  { const half8* src = (const half8*)(enc_out + (size_t)b*512*128);
    for (int i = tid; i < 8192; i += 512) {
      half8 v = src[i];
      int s = i >> 4, h0 = (i & 15) * 8, sg = s >> 3, s7 = s & 7;
      #pragma unroll
      for (int j = 0; j < 8; ++j) {
        int h = h0 + j;
        sm.ET[h*512 + (((sg ^ (h & 7) ^ ((h >> 3) & 7)) << 3)) + s7] = v[j];
      }
    } }
  if (tid < 128) { float hv = hfin[(size_t)b*128 + tid];
    sm.hsm[tid] = hv; sm.hh[tid] = (_Float16)hv; sm.cxh[0][128 + tid] = (_Float16)hv; }
  if (tid < 32) {
    // d32 = y0 - out1(h0)   (exact fp32)
    float o1v = out1_b[tid];
    for (int h = 0; h < 128; ++h) o1v += out1_W[tid*128 + h] * hfin[(size_t)b*128 + h];
    sm.d32[tid] = xb[((size_t)b*512 + 511)*32 + tid] - o1v;
  }
  __syncthreads();
  float c0reg = 0.f;     // per-thread (s = tid) step-0 correction
  #pragma unroll 8
  for (int f = 0; f < 32; ++f) c0reg += sm.d32[f] * attn_W[tid*160 + 128 + f];

  const half8 Az = {};
  const int hrow = wid*16 + l15;                     // P3 B-operand row
  const int hswz = (hrow & 7) ^ ((hrow >> 3) & 7);   // its swizzle key

  for (int tt = 0; tt < TO; ++tt) {
    _Float16* cxhR = sm.cxh[tt & 1];         // read buffer (ctx_t | h_{t-1})
    _Float16* cxhW = sm.cxh[(tt & 1) ^ 1];   // write buffer (h_t)

    // ---- P1: fused logits MFMA (K=128, aF regs) + no-max wave softmax partial ----
    half8 A[4];
    #pragma unroll
    for (int kb = 0; kb < 4; ++kb)
      A[kb] = (l15 == 0) ? *(const half8*)&sm.hh[kb*32 + lq*8] : Az;
    f32x4 CL[4];
    #pragma unroll
    for (int stt = 0; stt < 4; ++stt) CL[stt] = (f32x4){0.f,0.f,0.f,0.f};
    #pragma unroll
    for (int stt = 0; stt < 4; ++stt)
      #pragma unroll
      for (int kb = 0; kb < 4; ++kb)
        CL[stt] = __builtin_amdgcn_mfma_f32_16x16x32_f16(A[kb], aF[stt][kb], CL[stt], 0, 0, 0);
    // redistribute: thread tid gets logit s = tid  (s = wid*64 + lq*16 + l15)
    float t0 = __shfl(CL[0][0], l15), t1 = __shfl(CL[1][0], l15);
    float t2 = __shfl(CL[2][0], l15), t3 = __shfl(CL[3][0], l15);
    float v = (lq == 0) ? t0 : (lq == 1) ? t1 : (lq == 2) ? t2 : t3;
    v += ab;
    if (tt == 0) v += c0reg;
    // |h|<1 and |A~ rows| bounded => |v| <~ 8: exp without max-subtraction is safe in fp32
    float ex = __builtin_amdgcn_exp2f(LOG2E*v);
    float sw = ex;
    #pragma unroll
    for (int off = 1; off < 64; off <<= 1) sw += __shfl_xor(sw, off);
    if (lane == 0) sm.red[wid] = sw;
    __syncthreads();  // B1

    // ---- P2: softmax finalize, write w fp16 ----
    float tot = sm.red[0];
    #pragma unroll
    for (int g = 1; g < 8; ++g) tot += sm.red[g];
    sm.wsm[tid] = (_Float16)(ex * __builtin_amdgcn_rcpf(tot));
    __syncthreads();  // B2

    // ---- P3: reload aF for next step (covered by P3+P4 compute), then ctx MFMA ----
    #pragma unroll
    for (int stt = 0; stt < 4; ++stt)
      #pragma unroll
      for (int kb = 0; kb < 4; ++kb)
        aF[stt][kb] = aFp[((wid*4 + stt)*4 + kb)*64 + lane];
    f32x4 Ca[2];
    Ca[0] = (f32x4){0.f,0.f,0.f,0.f}; Ca[1] = (f32x4){0.f,0.f,0.f,0.f};
    #pragma unroll
    for (int kb = 0; kb < 16; ++kb) {
      const half8 bet = *(const half8*)&sm.ET[hrow*512 + (((kb*4 + lq) ^ hswz) << 3)];
      const half8 aw  = (l15 == 0) ? *(const half8*)&sm.wsm[kb*32 + lq*8] : Az;
      Ca[kb & 1] = __builtin_amdgcn_mfma_f32_16x16x32_f16(aw, bet, Ca[kb & 1], 0, 0, 0);
    }
    if (lane < 16)
      cxhR[wid*16 + l15] = (_Float16)(Ca[0][0] + Ca[1][0]);
    __syncthreads();  // B3

    // ---- P4: GRU MFMA (persistent B) + in-register gates ----
    half8 Ag[8];
    #pragma unroll
    for (int kb = 0; kb < 8; ++kb)
      Ag[kb] = (l15 == 0) ? *(const half8*)&cxhR[kb*32 + lq*8] : Az;
    f32x4 Cr, Cz, Cnh4, Cni4;
    Cr = (f32x4){0.f,0.f,0.f,0.f}; Cz = (f32x4){0.f,0.f,0.f,0.f};
    Cnh4 = (f32x4){0.f,0.f,0.f,0.f}; Cni4 = (f32x4){0.f,0.f,0.f,0.f};
    #pragma unroll
    for (int kb = 0; kb < 8; ++kb) {
      Cr = __builtin_amdgcn_mfma_f32_16x16x32_f16(Ag[kb], pRzR[kb], Cr, 0, 0, 0);
      Cz = __builtin_amdgcn_mfma_f32_16x16x32_f16(Ag[kb], pRzZ[kb], Cz, 0, 0, 0);
    }
    #pragma unroll
    for (int kb = 0; kb < 4; ++kb) {
      Cnh4 = __builtin_amdgcn_mfma_f32_16x16x32_f16(Ag[4 + kb], pNh[kb], Cnh4, 0, 0, 0);
      Cni4 = __builtin_amdgcn_mfma_f32_16x16x32_f16(Ag[kb],     pNi[kb], Cni4, 0, 0, 0);
    }
    if (lane < 16) {
      float xr = Cr[0] + bR, xz = Cz[0] + bZ;
      float r = __builtin_amdgcn_rcpf(1.f + __builtin_amdgcn_exp2f(-LOG2E*xr));
      float z = __builtin_amdgcn_rcpf(1.f + __builtin_amdgcn_exp2f(-LOG2E*xz));
      float narg = (Cni4[0] + bNI) + r * (Cnh4[0] + bNH);
      float n = 1.f - 2.f*__builtin_amdgcn_rcpf(__builtin_amdgcn_exp2f((2.f*LOG2E)*narg) + 1.f);
      float hnew = n + z*(sm.hsm[jg] - n);
      sm.hsm[jg] = hnew;
      _Float16 hf = (_Float16)hnew;
      sm.hh[jg] = hf;                      // next P1 A (after B4)
      cxhW[128 + jg] = hf;                 // next P4 A
      sm.hist[tt*128 + jg] = hf;           // epilogue
    }
    __syncthreads();  // B4
  }

  // ---- epilogue: out1+out2 for all 24 steps, wave 0, batched M=16 MFMA ----
  if (wid == 0) {
    #pragma unroll
    for (int chunk = 0; chunk < 2; ++chunk) {
      half8 Ae[4];
      #pragma unroll
      for (int kb = 0; kb < 4; ++kb) {
        int step = chunk*16 + l15;
        Ae[kb] = (step < TO) ? *(const half8*)&sm.hist[step*128 + kb*32 + lq*8] : Az;
      }
      f32x4 C0, C1;
      C0 = (f32x4){0.f,0.f,0.f,0.f}; C1 = (f32x4){0.f,0.f,0.f,0.f};
      #pragma unroll
      for (int kb = 0; kb < 4; ++kb) {
        C0 = __builtin_amdgcn_mfma_f32_16x16x32_f16(Ae[kb], oFp[kb*64 + lane],       C0, 0, 0, 0);
        C1 = __builtin_amdgcn_mfma_f32_16x16x32_f16(Ae[kb], oFp[(4 + kb)*64 + lane], C1, 0, 0, 0);
      }
      #pragma unroll
      for (int i = 0; i < 4; ++i) {
        int row = lq*4 + i, step = chunk*16 + row;
        float y0 = C0[i] + o1b0, y1 = C1[i] + o1b1;
        float part = fmaxf(y0, 0.f)*o2w0 + fmaxf(y1, 0.f)*o2w1;
        #pragma unroll
        for (int off = 1; off < 16; off <<= 1) part += __shfl_xor(part, off, 16);
        if (l15 == 0 && step < TO)
          out[(size_t)b*TO + step] = fmaxf(part + o2b, 0.f);
      }
    }
  }
}

extern "C" void kernel_launch(void* const* d_in, const int* in_sizes, int n_in,
                              void* d_out, int out_size, void* d_ws, size_t ws_size,
                              hipStream_t stream) {
  const float* xb      = (const float*)d_in[0];
  const float* enc_Wih = (const float*)d_in[1];
  const float* enc_Whh = (const float*)d_in[2];
  const float* enc_bih = (const float*)d_in[3];
  const float* enc_bhh = (const float*)d_in[4];
  const float* attn_W  = (const float*)d_in[5];
  const float* attn_b  = (const float*)d_in[6];
  const float* dec_Wih = (const float*)d_in[7];
  const float* dec_Whh = (const float*)d_in[8];
  const float* dec_bih = (const float*)d_in[9];
  const float* dec_bhh = (const float*)d_in[10];
  const float* out1_W  = (const float*)d_in[11];
  const float* out1_b  = (const float*)d_in[12];
  const float* out2_W  = (const float*)d_in[13];
  const float* out2_b  = (const float*)d_in[14];

  char* ws = (char*)d_ws;
  __half* enc_out = (__half*)(ws + OFF_ENCOUT);
  float*  hfin    = (float*)(ws + OFF_HFIN);
  __half* attnF   = (__half*)(ws + OFF_ATTNF);
  float*  attnB   = (float*)(ws + OFF_ATTNB);
  __half* decF    = (__half*)(ws + OFF_DECF);
  __half* out1F   = (__half*)(ws + OFF_OUT1F);
  __half* Wf      = (__half*)(ws + OFF_WF);

  prep_kernel<<<900, 256, 0, stream>>>(attn_W, attn_b, dec_Wih, dec_Whh, out1_W, out1_b,
                                       enc_Wih, enc_Whh, attnF, attnB, decF, out1F, Wf);
  enc_kernel<<<256, 256, 0, stream>>>(xb, Wf, enc_bih, enc_bhh, enc_out, hfin);
  dec_kernel<<<2048, 512, 0, stream>>>(xb, enc_out, hfin, attnF, attnB, attn_W, decF, out1F,
                                       dec_bih, dec_bhh, out1_W, out1_b, out2_W, out2_b,
                                       (float*)d_out);
}

// Round 16
// 1020.825 us; speedup vs baseline: 1.1423x; 1.0079x over previous
//
#include <hip/hip_runtime.h>
#include <hip/hip_fp16.h>

#define BB 2048
#define SS 512
#define FF 32
#define HH 128
#define TO 24
#define LOG2E 1.4426950408889634f

typedef unsigned int uint;
using half4 = __attribute__((ext_vector_type(4))) _Float16;
using half8 = __attribute__((ext_vector_type(8))) _Float16;
using f32x4 = __attribute__((ext_vector_type(4))) float;

// ---- workspace layout (bytes) ----
#define OFF_ENCOUT 0ull                                      // half[B][S][H]
#define OFF_HFIN  (OFF_ENCOUT + (size_t)BB*SS*HH*2)          // float[B][H]
#define OFF_ATTNF (OFF_HFIN + (size_t)BB*HH*4)               // half[65536]  fused logits B-frags (K=128)
#define OFF_ATTNB (OFF_ATTNF + (size_t)65536*2)              // float[512]   fused logit bias
#define OFF_DECF  (OFF_ATTNB + (size_t)512*4)                // half[98304]  GRU B-frags
#define OFF_OUT1F (OFF_DECF + (size_t)98304*2)               // half[4096]   out1 B-frags
#define OFF_WF    (OFF_OUT1F + (size_t)4096*2)               // half[61440]  enc B-frags

// ================= prep: fuse attn+out1, pack all weights into MFMA frag order =================
__global__ void prep_kernel(const float* attn_W, const float* attn_b,
                            const float* dec_Wih, const float* dec_Whh,
                            const float* out1_W, const float* out1_b,
                            const float* enc_Wih, const float* enc_Whh,
                            __half* attnF, float* attnB, __half* decF, __half* out1F, __half* Wf) {
  int i = blockIdx.x * 256 + threadIdx.x;
  if (i < 65536) {
    // fused A~[s][h] frags: idx = ((w*4+st)*4+kb)*512 + l*8 + e
    int e = i & 7, l = (i >> 3) & 63, kb = (i >> 9) & 3, st = (i >> 11) & 3, w = i >> 13;
    int h = kb*32 + ((l >> 4) << 3) + e;
    int s = w*64 + st*16 + (l & 15);
    float acc = attn_W[s*160 + h];
    #pragma unroll 8
    for (int f = 0; f < 32; ++f) acc += out1_W[f*128 + h] * attn_W[s*160 + 128 + f];
    attnF[i] = __float2half(acc);
    return;
  }
  i -= 65536;
  if (i < 512) {               // b~[s] = attn_b[s] + sum_f out1_b[f]*A_y[s][f]
    float acc = attn_b[i];
    #pragma unroll 8
    for (int f = 0; f < 32; ++f) acc += out1_b[f] * attn_W[i*160 + 128 + f];
    attnB[i] = acc;
    return;
  }
  i -= 512;
  if (i < 98304) {
    int e = i & 7, l = (i >> 3) & 63, fi = (i >> 9) % 48, w = i / 24576;
    int lq = l >> 4, l15 = l & 15;
    float val;
    if (fi < 32) {            // r/z combined [ctx|h] K=256
      int g2 = fi >> 4, sub = (fi >> 3) & 1, kb = fi & 7;
      int k = kb*32 + lq*8 + e, j = w*32 + sub*16 + l15, jg = g2*128 + j;
      val = (k < 128) ? dec_Wih[jg*128 + k] : dec_Whh[jg*128 + (k - 128)];
    } else {                  // nh (Whh) then ni (Wih), K=128 each
      int f2 = fi - 32, cat = f2 >> 3, sub = (f2 >> 2) & 1, kb4 = f2 & 3;
      int k = kb4*32 + lq*8 + e, j = 256 + w*32 + sub*16 + l15;
      val = cat ? dec_Wih[j*128 + k] : dec_Whh[j*128 + k];
    }
    decF[i] = __float2half(val);
    return;
  }
  i -= 98304;
  if (i < 4096) {             // out1F frags: tile(2) x kb(4) x lane x e
    int e = i & 7, l = (i >> 3) & 63, kb = (i >> 9) & 3, tile = (i >> 11) & 1;
    int k = kb*32 + ((l >> 4) << 3) + e;
    int f = tile*16 + (l & 15);
    out1F[i] = __float2half(out1_W[f*128 + k]);
    return;
  }
  i -= 4096;
  if (i < 61440) {
    int e = i & 7, l = (i >> 3) & 63, q = i >> 9;
    int kb = q % 5, tt = (q / 5) % 6, w = q / 30;
    int g = tt >> 1, sub = tt & 1;
    int k = kb*32 + ((l >> 4) << 3) + e;
    int J = g*128 + w*32 + sub*16 + (l & 15);
    float v = (k < 128) ? enc_Whh[J*128 + k] : enc_Wih[J*32 + (k - 128)];
    Wf[i] = __float2half(v);
  }
}

// ================= encoder: MFMA, 8 batches/block, ping-pong hx, 1 barrier/step =================
#define HXS 168

__global__ void __launch_bounds__(256, 1) enc_kernel(
    const float* __restrict__ xb, const __half* __restrict__ Wf,
    const float* __restrict__ bih, const float* __restrict__ bhh,
    __half* __restrict__ enc_out, float* __restrict__ hfin) {
  __shared__ __align__(16) _Float16 hx[2][16][HXS];   // rows 0..7 live, 8..15 zero
  const int tid  = threadIdx.x;
  const int lane = tid & 63, wid = tid >> 6;
  const int l15  = lane & 15, lq = lane >> 4;
  const int b0   = blockIdx.x * 8;

  half8 Bf[6][5];
  { const half8* wfp = (const half8*)Wf;
    #pragma unroll
    for (int tt = 0; tt < 6; ++tt)
      #pragma unroll
      for (int kb = 0; kb < 5; ++kb)
        Bf[tt][kb] = wfp[((wid*6 + tt)*5 + kb)*64 + lane];
  }

  float br[2], bz[2], bnh[2], bni[2];
  #pragma unroll
  for (int sub = 0; sub < 2; ++sub) {
    int j = wid*32 + sub*16 + l15;
    br[sub]  = bih[j]       + bhh[j];
    bz[sub]  = bih[128 + j] + bhh[128 + j];
    bnh[sub] = bhh[256 + j];
    bni[sub] = bih[256 + j];
  }
  float hreg[2][4] = {{0.f,0.f,0.f,0.f},{0.f,0.f,0.f,0.f}};

  const int m2 = tid >> 5, c2 = tid & 31;   // staging: 8 rows x 32 cols
  const float* xbase = xb + ((size_t)(b0 + m2)*512)*32 + c2;

  for (int i = tid; i < 2*16*HXS; i += 256) (&hx[0][0][0])[i] = (_Float16)0.f;
  __syncthreads();
  hx[0][m2][128 + c2] = (_Float16)xbase[0];
  __syncthreads();

  float xq_next = xbase[1*32];    // x_{t+1} pipeline register

  int p = 0;
  for (int t = 0; t < 512; ++t) {
    const int tn2 = (t < 510) ? t + 2 : 511;
    float xq_new = xbase[(size_t)tn2*32];

    half8 A[5];
    #pragma unroll
    for (int kb = 0; kb < 5; ++kb)
      A[kb] = *(const half8*)&hx[p][l15][kb*32 + lq*8];

    f32x4 Cr[2], Cz[2], Cnh[2], Cni[2];
    #pragma unroll
    for (int sub = 0; sub < 2; ++sub) {
      Cr[sub] = (f32x4){0.f,0.f,0.f,0.f};
      Cz[sub] = (f32x4){0.f,0.f,0.f,0.f};
      Cnh[sub] = (f32x4){0.f,0.f,0.f,0.f};
      Cni[sub] = (f32x4){0.f,0.f,0.f,0.f};
    }
    #pragma unroll
    for (int sub = 0; sub < 2; ++sub) {
      #pragma unroll
      for (int kb = 0; kb < 5; ++kb) {
        Cr[sub] = __builtin_amdgcn_mfma_f32_16x16x32_f16(A[kb], Bf[sub][kb],     Cr[sub], 0, 0, 0);
        Cz[sub] = __builtin_amdgcn_mfma_f32_16x16x32_f16(A[kb], Bf[2 + sub][kb], Cz[sub], 0, 0, 0);
      }
      #pragma unroll
      for (int kb = 0; kb < 4; ++kb)
        Cnh[sub] = __builtin_amdgcn_mfma_f32_16x16x32_f16(A[kb], Bf[4 + sub][kb], Cnh[sub], 0, 0, 0);
      Cni[sub] = __builtin_amdgcn_mfma_f32_16x16x32_f16(A[4], Bf[4 + sub][4], Cni[sub], 0, 0, 0);
    }

    // gates: write h_t and x_{t+1} into the OTHER buffer
    #pragma unroll
    for (int sub = 0; sub < 2; ++sub)
      #pragma unroll
      for (int i = 0; i < 4; ++i) {
        float xr = Cr[sub][i] + br[sub];
        float xz = Cz[sub][i] + bz[sub];
        float r = __builtin_amdgcn_rcpf(1.f + __builtin_amdgcn_exp2f(-LOG2E*xr));
        float z = __builtin_amdgcn_rcpf(1.f + __builtin_amdgcn_exp2f(-LOG2E*xz));
        float narg = (Cni[sub][i] + bni[sub]) + r * (Cnh[sub][i] + bnh[sub]);
        float n = 1.f - 2.f*__builtin_amdgcn_rcpf(__builtin_amdgcn_exp2f((2.f*LOG2E)*narg) + 1.f);
        float hnew = n + z*(hreg[sub][i] - n);
        hreg[sub][i] = hnew;
        if (lq < 2)
          hx[p ^ 1][4*lq + i][wid*32 + sub*16 + l15] = (_Float16)hnew;
      }
    hx[p ^ 1][m2][128 + c2] = (_Float16)xq_next;
    xq_next = xq_new;
    __syncthreads();   // single barrier per step

    { half4 hv = *(const half4*)&hx[p ^ 1][m2][c2*4];
      *(half4*)((void*)&enc_out[((size_t)(b0 + m2)*512 + t)*128 + c2*4]) = hv; }
    p ^= 1;
  }

  if (lq < 2)
    #pragma unroll
    for (int sub = 0; sub < 2; ++sub)
      #pragma unroll
      for (int i = 0; i < 4; ++i)
        hfin[(size_t)(b0 + 4*lq + i)*128 + wid*32 + sub*16 + l15] = hreg[sub][i];
}

// ================= decoder: 3 barriers/step — unnormalized-softmax ctx (scale after MFMA),
//                   persistent GRU frags, pipelined attnF, batched epilogue ============
struct DecSmem {
  _Float16 ET[128*512];   // 128 KB, swizzled: (h,s) -> h*512 + ((s>>3 ^ (h&7) ^ ((h>>3)&7))<<3) + (s&7)
  _Float16 wsm[512];      // UNNORMALIZED exp(logit) fp16
  float hsm[128];         // h fp32 (gate carry)
  _Float16 hh[128];       // h fp16 (P1 A operand)
  _Float16 cxh[2][256];   // ping-pong [ctx | h]
  _Float16 hist[TO*128];  // h history for out epilogue
  float red[8];           // per-wave exp-sums
  float d32[32];          // y0 - out1(h0)
};

__global__ void __launch_bounds__(512)
__attribute__((amdgpu_waves_per_eu(2, 2)))
dec_kernel(const float* __restrict__ xb,
    const __half* __restrict__ enc_out, const float* __restrict__ hfin,
    const __half* __restrict__ attnF, const float* __restrict__ attnB,
    const float* __restrict__ attn_W,
    const __half* __restrict__ decF, const __half* __restrict__ out1F,
    const float* __restrict__ dbih, const float* __restrict__ dbhh,
    const float* __restrict__ out1_W, const float* __restrict__ out1_b,
    const float* __restrict__ out2_W, const float* __restrict__ out2_b,
    float* __restrict__ out) {
  __shared__ __align__(16) DecSmem sm;
  const int tid = threadIdx.x, lane = tid & 63, wid = tid >> 6;
  const int l15 = lane & 15, lq = lane >> 4;
  const int b = blockIdx.x;

  const half8* aFp = (const half8*)attnF;
  const half8* dFp = (const half8*)decF;
  const half8* oFp = (const half8*)out1F;
  const int Wb = wid >> 1, sb = wid & 1;

  // ---- per-thread scalar params ----
  const float ab = attnB[tid];                       // fused logit bias for s = tid
  const int jg = wid*16 + l15;                       // this wave's gate col
  const float bR  = dbih[jg]       + dbhh[jg];
  const float bZ  = dbih[128 + jg] + dbhh[128 + jg];
  const float bNH = dbhh[256 + jg];
  const float bNI = dbih[256 + jg];
  const float o1b0 = out1_b[l15], o1b1 = out1_b[16 + l15];
  const float o2w0 = out2_W[l15], o2w1 = out2_W[16 + l15];
  const float o2b  = out2_b[0];

  // ---- persistent GRU B-frags: 24 half8 = 96 VGPR, live across the whole tt-loop ----
  half8 pRzR[8], pRzZ[8], pNh[4], pNi[4];
  #pragma unroll
  for (int kb = 0; kb < 8; ++kb) {
    pRzR[kb] = dFp[(Wb*48 +      sb*8 + kb)*64 + lane];
    pRzZ[kb] = dFp[(Wb*48 + 16 + sb*8 + kb)*64 + lane];
  }
  #pragma unroll
  for (int kb = 0; kb < 4; ++kb) {
    pNh[kb] = dFp[(Wb*48 + 32 + sb*4 + kb)*64 + lane];
    pNi[kb] = dFp[(Wb*48 + 40 + sb*4 + kb)*64 + lane];
  }
  // ---- attnF pipeline buffer: step-0 frags (reloaded each step at P3-start) ----
  half8 aF[4][4];
  #pragma unroll
  for (int stt = 0; stt < 4; ++stt)
    #pragma unroll
    for (int kb = 0; kb < 4; ++kb)
      aF[stt][kb] = aFp[((wid*4 + stt)*4 + kb)*64 + lane];

  // ---- staging: E transposed+swizzled into LDS; h0; step-0 logit correction ----
  { const half8* src = (const half8*)(enc_out + (size_t)b*512*128);
    for (int i = tid; i < 8192; i += 512) {
      half8 v = src[i];
      int s = i >> 4, h0 = (i & 15) * 8, sg = s >> 3, s7 = s & 7;
      #pragma unroll
      for (int j = 0; j < 8; ++j) {
        int h = h0 + j;
        sm.ET[h*512 + (((sg ^ (h & 7) ^ ((h >> 3) & 7)) << 3)) + s7] = v[j];
      }
    } }
  if (tid < 128) { float hv = hfin[(size_t)b*128 + tid];
    sm.hsm[tid] = hv; sm.hh[tid] = (_Float16)hv; sm.cxh[0][128 + tid] = (_Float16)hv; }
  if (tid < 32) {
    // d32 = y0 - out1(h0)   (exact fp32)
    float o1v = out1_b[tid];
    for (int h = 0; h < 128; ++h) o1v += out1_W[tid*128 + h] * hfin[(size_t)b*128 + h];
    sm.d32[tid] = xb[((size_t)b*512 + 511)*32 + tid] - o1v;
  }
  __syncthreads();
  float c0reg = 0.f;     // per-thread (s = tid) step-0 correction
  #pragma unroll 8
  for (int f = 0; f < 32; ++f) c0reg += sm.d32[f] * attn_W[tid*160 + 128 + f];

  const half8 Az = {};
  const int hrow = wid*16 + l15;                     // P3 B-operand row
  const int hswz = (hrow & 7) ^ ((hrow >> 3) & 7);   // its swizzle key

  for (int tt = 0; tt < TO; ++tt) {
    _Float16* cxhR = sm.cxh[tt & 1];         // read buffer (ctx_t | h_{t-1})
    _Float16* cxhW = sm.cxh[(tt & 1) ^ 1];   // write buffer (h_t)

    // ---- P1: fused logits MFMA (K=128, aF regs) + UNNORMALIZED exp + wave sum ----
    half8 A[4];
    #pragma unroll
    for (int kb = 0; kb < 4; ++kb)
      A[kb] = (l15 == 0) ? *(const half8*)&sm.hh[kb*32 + lq*8] : Az;
    f32x4 CL[4];
    #pragma unroll
    for (int stt = 0; stt < 4; ++stt) CL[stt] = (f32x4){0.f,0.f,0.f,0.f};
    #pragma unroll
    for (int stt = 0; stt < 4; ++stt)
      #pragma unroll
      for (int kb = 0; kb < 4; ++kb)
        CL[stt] = __builtin_amdgcn_mfma_f32_16x16x32_f16(A[kb], aF[stt][kb], CL[stt], 0, 0, 0);
    // redistribute: thread tid gets logit s = tid  (s = wid*64 + lq*16 + l15)
    float t0 = __shfl(CL[0][0], l15), t1 = __shfl(CL[1][0], l15);
    float t2 = __shfl(CL[2][0], l15), t3 = __shfl(CL[3][0], l15);
    float v = (lq == 0) ? t0 : (lq == 1) ? t1 : (lq == 2) ? t2 : t3;
    v += ab;
    if (tt == 0) v += c0reg;
    // |v| <~ 8 -> exp safe in fp32/fp16 WITHOUT max-subtraction; store unnormalized
    float ex = __builtin_amdgcn_exp2f(LOG2E*v);
    sm.wsm[tid] = (_Float16)ex;              // unnormalized weight (pre-B1)
    float sw = ex;
    #pragma unroll
    for (int off = 1; off < 64; off <<= 1) sw += __shfl_xor(sw, off);
    if (lane == 0) sm.red[wid] = sw;
    __syncthreads();  // B1  (covers wsm + red)

    // ---- P3: reload aF for next step, ctx = (w_unnorm @ E) * rcp(tot) ----
    #pragma unroll
    for (int stt = 0; stt < 4; ++stt)
      #pragma unroll
      for (int kb = 0; kb < 4; ++kb)
        aF[stt][kb] = aFp[((wid*4 + stt)*4 + kb)*64 + lane];
    float tot = sm.red[0];
    #pragma unroll
    for (int g = 1; g < 8; ++g) tot += sm.red[g];
    const float itot = __builtin_amdgcn_rcpf(tot);
    f32x4 Ca[2];
    Ca[0] = (f32x4){0.f,0.f,0.f,0.f}; Ca[1] = (f32x4){0.f,0.f,0.f,0.f};
    #pragma unroll
    for (int kb = 0; kb < 16; ++kb) {
      const half8 bet = *(const half8*)&sm.ET[hrow*512 + (((kb*4 + lq) ^ hswz) << 3)];
      const half8 aw  = (l15 == 0) ? *(const half8*)&sm.wsm[kb*32 + lq*8] : Az;
      Ca[kb & 1] = __builtin_amdgcn_mfma_f32_16x16x32_f16(aw, bet, Ca[kb & 1], 0, 0, 0);
    }
    if (lane < 16)
      cxhR[wid*16 + l15] = (_Float16)((Ca[0][0] + Ca[1][0]) * itot);
    __syncthreads();  // B3

    // ---- P4: GRU MFMA (persistent B) + in-register gates ----
    half8 Ag[8];
    #pragma unroll
    for (int kb = 0; kb < 8; ++kb)
      Ag[kb] = (l15 == 0) ? *(const half8*)&cxhR[kb*32 + lq*8] : Az;
    f32x4 Cr, Cz, Cnh4, Cni4;
    Cr = (f32x4){0.f,0.f,0.f,0.f}; Cz = (f32x4){0.f,0.f,0.f,0.f};
    Cnh4 = (f32x4){0.f,0.f,0.f,0.f}; Cni4 = (f32x4){0.f,0.f,0.f,0.f};
    #pragma unroll
    for (int kb = 0; kb < 8; ++kb) {
      Cr = __builtin_amdgcn_mfma_f32_16x16x32_f16(Ag[kb], pRzR[kb], Cr, 0, 0, 0);
      Cz = __builtin_amdgcn_mfma_f32_16x16x32_f16(Ag[kb], pRzZ[kb], Cz, 0, 0, 0);
    }
    #pragma unroll
    for (int kb = 0; kb < 4; ++kb) {
      Cnh4 = __builtin_amdgcn_mfma_f32_16x16x32_f16(Ag[4 + kb], pNh[kb], Cnh4, 0, 0, 0);
      Cni4 = __builtin_amdgcn_mfma_f32_16x16x32_f16(Ag[kb],     pNi[kb], Cni4, 0, 0, 0);
    }
    if (lane < 16) {
      float xr = Cr[0] + bR, xz = Cz[0] + bZ;
      float r = __builtin_amdgcn_rcpf(1.f + __builtin_amdgcn_exp2f(-LOG2E*xr));
      float z = __builtin_amdgcn_rcpf(1.f + __builtin_amdgcn_exp2f(-LOG2E*xz));
      float narg = (Cni4[0] + bNI) + r * (Cnh4[0] + bNH);
      float n = 1.f - 2.f*__builtin_amdgcn_rcpf(__builtin_amdgcn_exp2f((2.f*LOG2E)*narg) + 1.f);
      float hnew = n + z*(sm.hsm[jg] - n);
      sm.hsm[jg] = hnew;
      _Float16 hf = (_Float16)hnew;
      sm.hh[jg] = hf;                      // next P1 A (after B4)
      cxhW[128 + jg] = hf;                 // next P4 A
      sm.hist[tt*128 + jg] = hf;           // epilogue
    }
    __syncthreads();  // B4
  }

  // ---- epilogue: out1+out2 for all 24 steps, wave 0, batched M=16 MFMA ----
  if (wid == 0) {
    #pragma unroll
    for (int chunk = 0; chunk < 2; ++chunk) {
      half8 Ae[4];
      #pragma unroll
      for (int kb = 0; kb < 4; ++kb) {
        int step = chunk*16 + l15;
        Ae[kb] = (step < TO) ? *(const half8*)&sm.hist[step*128 + kb*32 + lq*8] : Az;
      }
      f32x4 C0, C1;
      C0 = (f32x4){0.f,0.f,0.f,0.f}; C1 = (f32x4){0.f,0.f,0.f,0.f};
      #pragma unroll
      for (int kb = 0; kb < 4; ++kb) {
        C0 = __builtin_amdgcn_mfma_f32_16x16x32_f16(Ae[kb], oFp[kb*64 + lane],       C0, 0, 0, 0);
        C1 = __builtin_amdgcn_mfma_f32_16x16x32_f16(Ae[kb], oFp[(4 + kb)*64 + lane], C1, 0, 0, 0);
      }
      #pragma unroll
      for (int i = 0; i < 4; ++i) {
        int row = lq*4 + i, step = chunk*16 + row;
        float y0 = C0[i] + o1b0, y1 = C1[i] + o1b1;
        float part = fmaxf(y0, 0.f)*o2w0 + fmaxf(y1, 0.f)*o2w1;
        #pragma unroll
        for (int off = 1; off < 16; off <<= 1) part += __shfl_xor(part, off, 16);
        if (l15 == 0 && step < TO)
          out[(size_t)b*TO + step] = fmaxf(part + o2b, 0.f);
      }
    }
  }
}

extern "C" void kernel_launch(void* const* d_in, const int* in_sizes, int n_in,
                              void* d_out, int out_size, void* d_ws, size_t ws_size,
                              hipStream_t stream) {
  const float* xb      = (const float*)d_in[0];
  const float* enc_Wih = (const float*)d_in[1];
  const float* enc_Whh = (const float*)d_in[2];
  const float* enc_bih = (const float*)d_in[3];
  const float* enc_bhh = (const float*)d_in[4];
  const float* attn_W  = (const float*)d_in[5];
  const float* attn_b  = (const float*)d_in[6];
  const float* dec_Wih = (const float*)d_in[7];
  const float* dec_Whh = (const float*)d_in[8];
  const float* dec_bih = (const float*)d_in[9];
  const float* dec_bhh = (const float*)d_in[10];
  const float* out1_W  = (const float*)d_in[11];
  const float* out1_b  = (const float*)d_in[12];
  const float* out2_W  = (const float*)d_in[13];
  const float* out2_b  = (const float*)d_in[14];

  char* ws = (char*)d_ws;
  __half* enc_out = (__half*)(ws + OFF_ENCOUT);
  float*  hfin    = (float*)(ws + OFF_HFIN);
  __half* attnF   = (__half*)(ws + OFF_ATTNF);
  float*  attnB   = (float*)(ws + OFF_ATTNB);
  __half* decF    = (__half*)(ws + OFF_DECF);
  __half* out1F   = (__half*)(ws + OFF_OUT1F);
  __half* Wf      = (__half*)(ws + OFF_WF);

  prep_kernel<<<900, 256, 0, stream>>>(attn_W, attn_b, dec_Wih, dec_Whh, out1_W, out1_b,
                                       enc_Wih, enc_Whh, attnF, attnB, decF, out1F, Wf);
  enc_kernel<<<256, 256, 0, stream>>>(xb, Wf, enc_bih, enc_bhh, enc_out, hfin);
  dec_kernel<<<2048, 512, 0, stream>>>(xb, enc_out, hfin, attnF, attnB, attn_W, decF, out1F,
                                       dec_bih, dec_bhh, out1_W, out1_b, out2_W, out2_b,
                                       (float*)d_out);
}